// Round 1
// baseline (2534.143 us; speedup 1.0000x reference)
//
#include <hip/hip_runtime.h>
#include <hip/hip_bf16.h>

// Transformer forward, f32 baseline.
// B=8 T=512 A=512 C=8 D=256 H=8 dh=32 FF=1024 DEC_FF=512 L=3
constexpr int CB = 8;
constexpr int CT = 512;
constexpr int CA = 512;
constexpr int CC = 8;
constexpr int CD = 256;
constexpr int CM = CB * CT;   // 4096 rows
constexpr float NEGV = -1.0e9f;

// ---------------- masks ----------------
__global__ void mask_prep_kernel(const int* __restrict__ tasks,
                                 const int* __restrict__ indices,
                                 int* __restrict__ asgn, int* __restrict__ fullm,
                                 int* __restrict__ padm) {
  int i = blockIdx.x * blockDim.x + threadIdx.x;   // 0..4095  (b*512 + t  /  b*512 + a)
  if (i >= CB * CT) return;
  asgn[i] = 0;
  const int* tp = tasks + i * 4;
  padm[i] = (tp[0] == -1) && (tp[1] == -1) && (tp[2] == -1) && (tp[3] == -1);
  const int* ip = indices + i * CC;
  int full = 1;
#pragma unroll
  for (int c = 0; c < CC; ++c) full &= (ip[c] != -1);
  fullm[i] = full;
}

__global__ void mask_assign_kernel(const int* __restrict__ indices, int* __restrict__ asgn) {
  int i = blockIdx.x * blockDim.x + threadIdx.x;   // 0..32767
  if (i >= CB * CA * CC) return;
  int b = i / (CA * CC);
  int idx = indices[i];
  if (idx >= 0) asgn[b * CT + idx] = 1;   // benign race: same value
}

// ---------------- embedding gather+sum ----------------
__global__ void embed_kernel(const int* __restrict__ toks, const float* __restrict__ table,
                             float* __restrict__ out, int nf) {
  int row = blockIdx.x;      // 0..4095
  int lane = threadIdx.x;    // 0..63, 4 floats each
  const int* tp = toks + row * nf;
  float4 acc = make_float4(0.f, 0.f, 0.f, 0.f);
  for (int f = 0; f < nf; ++f) {
    int t = 1 + tp[f];
    float4 v = *(const float4*)(table + ((size_t)f * 33 + t) * CD + lane * 4);
    acc.x += v.x; acc.y += v.y; acc.z += v.z; acc.w += v.w;
  }
  *(float4*)(out + (size_t)row * CD + lane * 4) = acc;
}

// ---------------- residual add + LayerNorm (in place on x) ----------------
__global__ void ln_add_kernel(float* __restrict__ x, const float* __restrict__ res,
                              const float* __restrict__ g, const float* __restrict__ b) {
  int row = blockIdx.x;
  int lane = threadIdx.x;   // 64 lanes, 4 floats each
  float4 xv = *(const float4*)(x + (size_t)row * CD + lane * 4);
  float4 rv = *(const float4*)(res + (size_t)row * CD + lane * 4);
  float v0 = xv.x + rv.x, v1 = xv.y + rv.y, v2 = xv.z + rv.z, v3 = xv.w + rv.w;
  float s = v0 + v1 + v2 + v3;
  float s2 = v0 * v0 + v1 * v1 + v2 * v2 + v3 * v3;
#pragma unroll
  for (int off = 32; off >= 1; off >>= 1) {
    s += __shfl_xor(s, off);
    s2 += __shfl_xor(s2, off);
  }
  float mean = s * (1.0f / CD);
  float var = s2 * (1.0f / CD) - mean * mean;
  float rstd = rsqrtf(var + 1e-5f);
  float4 gv = *(const float4*)(g + lane * 4);
  float4 bv = *(const float4*)(b + lane * 4);
  float4 o;
  o.x = (v0 - mean) * rstd * gv.x + bv.x;
  o.y = (v1 - mean) * rstd * gv.y + bv.y;
  o.z = (v2 - mean) * rstd * gv.z + bv.z;
  o.w = (v3 - mean) * rstd * gv.w + bv.w;
  *(float4*)(x + (size_t)row * CD + lane * 4) = o;
}

// ---------------- generic tiled f32 GEMM: C = A @ B (+bias)(+relu), opt B^T ----------------
// Tile 64x64, BK=16, 256 threads, 4x4 per thread. All dims divide evenly.
template <bool TRANSB, bool BIAS, bool RELU>
__global__ __launch_bounds__(256) void gemm_kernel(
    const float* __restrict__ A, const float* __restrict__ Bm,
    const float* __restrict__ bias, float* __restrict__ C,
    int Mdim, int Ndim, int Kdim, long long sA, long long sB, long long sC) {
  __shared__ float As[16][64];
  __shared__ float Bs[16][64];
  const float* Ab = A + (size_t)blockIdx.z * sA;
  const float* Bb = Bm + (size_t)blockIdx.z * sB;
  float* Cb = C + (size_t)blockIdx.z * sC;
  const int bm = blockIdx.x * 64, bn = blockIdx.y * 64;
  const int tx = threadIdx.x & 15, ty = threadIdx.x >> 4;
  const int lr = threadIdx.x >> 2, lk = (threadIdx.x & 3) << 2;
  const int br = threadIdx.x >> 4, bc = (threadIdx.x & 15) << 2;
  float acc[4][4] = {};
  for (int k0 = 0; k0 < Kdim; k0 += 16) {
    float4 av = *(const float4*)(Ab + (size_t)(bm + lr) * Kdim + k0 + lk);
    As[lk + 0][lr] = av.x; As[lk + 1][lr] = av.y;
    As[lk + 2][lr] = av.z; As[lk + 3][lr] = av.w;
    if (!TRANSB) {
      *(float4*)&Bs[br][bc] = *(const float4*)(Bb + (size_t)(k0 + br) * Ndim + bn + bc);
    } else {
      float4 bv = *(const float4*)(Bb + (size_t)(bn + lr) * Kdim + k0 + lk);
      Bs[lk + 0][lr] = bv.x; Bs[lk + 1][lr] = bv.y;
      Bs[lk + 2][lr] = bv.z; Bs[lk + 3][lr] = bv.w;
    }
    __syncthreads();
#pragma unroll
    for (int kk = 0; kk < 16; ++kk) {
      float4 a4 = *(const float4*)&As[kk][ty << 2];
      float4 b4 = *(const float4*)&Bs[kk][tx << 2];
      float avv[4] = {a4.x, a4.y, a4.z, a4.w};
      float bvv[4] = {b4.x, b4.y, b4.z, b4.w};
#pragma unroll
      for (int i = 0; i < 4; ++i)
#pragma unroll
        for (int j = 0; j < 4; ++j) acc[i][j] = fmaf(avv[i], bvv[j], acc[i][j]);
    }
    __syncthreads();
  }
#pragma unroll
  for (int i = 0; i < 4; ++i) {
    int r = bm + (ty << 2) + i;
    float4 o;
    float tmp[4];
#pragma unroll
    for (int j = 0; j < 4; ++j) {
      float v = acc[i][j];
      if (BIAS) v += bias[bn + (tx << 2) + j];
      if (RELU) v = fmaxf(v, 0.0f);
      tmp[j] = v;
    }
    o.x = tmp[0]; o.y = tmp[1]; o.z = tmp[2]; o.w = tmp[3];
    *(float4*)(Cb + (size_t)r * Ndim + bn + (tx << 2)) = o;
  }
}

// ---------------- attention over flat-chunk heads ----------------
// q/k/v/o: flat (B*T*D); head (b,h) rows are 32-float chunks at (b*8+h)*16384 + x*32.
// MODE 0: encoder self-attn, key masked by padm[b,kx].
// MODE 1: decoder cross-attn, masked = asgn[b,qx]|padm[b,qx]|fullm[b,kx].
template <int MODE>
__global__ __launch_bounds__(256) void attn_kernel(
    const float* __restrict__ qb, const float* __restrict__ kb, const float* __restrict__ vb,
    float* __restrict__ ob,
    const int* __restrict__ asgn, const int* __restrict__ fullm, const int* __restrict__ padm) {
  __shared__ float Ks[512 * 36];   // stride 36 to break bank conflicts
  __shared__ float Vs[512 * 32];
  __shared__ float Ps[4][512];
  const int bh = blockIdx.x;
  const int b = bh >> 3;
  const size_t base = (size_t)bh * (512 * 32);
  const int tid = threadIdx.x;
  for (int i = tid; i < 4096; i += 256) {
    int x = i >> 3, g = (i & 7) << 2;
    *(float4*)&Ks[x * 36 + g] = *(const float4*)(kb + base + x * 32 + g);
    *(float4*)&Vs[x * 32 + g] = *(const float4*)(vb + base + x * 32 + g);
  }
  __syncthreads();
  const int wave = tid >> 6, lane = tid & 63;
  float* Pw = Ps[wave];
  const int q0 = blockIdx.y * 64 + wave * 16;
  int kmask[8];
#pragma unroll
  for (int m = 0; m < 8; ++m) {
    int kx = lane + (m << 6);
    kmask[m] = (MODE == 0) ? padm[b * CT + kx] : fullm[b * CA + kx];
  }
  for (int qi = 0; qi < 16; ++qi) {
    const int qx = q0 + qi;
    const float* Qr = qb + base + qx * 32;
    float qreg[32];
#pragma unroll
    for (int g = 0; g < 8; ++g) {
      float4 t4 = *(const float4*)(Qr + g * 4);
      qreg[g * 4 + 0] = t4.x; qreg[g * 4 + 1] = t4.y;
      qreg[g * 4 + 2] = t4.z; qreg[g * 4 + 3] = t4.w;
    }
    int qmask = 0;
    if (MODE == 1) qmask = asgn[b * CT + qx] | padm[b * CT + qx];
    float s[8];
    int mk[8];
#pragma unroll
    for (int m = 0; m < 8; ++m) {
      int kx = lane + (m << 6);
      const float* Kr = &Ks[kx * 36];
      float acc = 0.f;
#pragma unroll
      for (int g = 0; g < 8; ++g) {
        float4 k4 = *(const float4*)(Kr + g * 4);
        acc = fmaf(qreg[g * 4 + 0], k4.x, acc);
        acc = fmaf(qreg[g * 4 + 1], k4.y, acc);
        acc = fmaf(qreg[g * 4 + 2], k4.z, acc);
        acc = fmaf(qreg[g * 4 + 3], k4.w, acc);
      }
      acc *= 0.17677669529663687f;   // 1/sqrt(32)
      int masked = (MODE == 1) ? (qmask | kmask[m]) : kmask[m];
      mk[m] = masked;
      s[m] = masked ? NEGV : acc;
    }
    float mx = s[0];
#pragma unroll
    for (int m = 1; m < 8; ++m) mx = fmaxf(mx, s[m]);
#pragma unroll
    for (int off = 32; off >= 1; off >>= 1) mx = fmaxf(mx, __shfl_xor(mx, off));
    float sum = 0.f, e[8];
#pragma unroll
    for (int m = 0; m < 8; ++m) { e[m] = __expf(s[m] - mx); sum += e[m]; }
#pragma unroll
    for (int off = 32; off >= 1; off >>= 1) sum += __shfl_xor(sum, off);
    float inv = 1.0f / sum;
#pragma unroll
    for (int m = 0; m < 8; ++m) Pw[lane + (m << 6)] = mk[m] ? 0.0f : e[m] * inv;
    __syncthreads();   // safety: ensure P visible before PV reads
    const int j = lane & 31, half = lane >> 5;
    const int x0 = half << 8;
    float oacc = 0.f;
    for (int xx4 = 0; xx4 < 64; ++xx4) {
      float4 p4 = *(const float4*)&Pw[x0 + (xx4 << 2)];
      const float* Vp = &Vs[(x0 + (xx4 << 2)) * 32 + j];
      oacc = fmaf(p4.x, Vp[0], oacc);
      oacc = fmaf(p4.y, Vp[32], oacc);
      oacc = fmaf(p4.z, Vp[64], oacc);
      oacc = fmaf(p4.w, Vp[96], oacc);
    }
    oacc += __shfl_xor(oacc, 32);
    if (lane < 32) ob[base + qx * 32 + j] = oacc;
    __syncthreads();
  }
}

// ---------------- final: 8*tanh(scores/16), mask, softmax over a, write transposed ----------------
__global__ void final_kernel(const float* __restrict__ scores,
                             const int* __restrict__ asgn, const int* __restrict__ fullm,
                             const int* __restrict__ padm, float* __restrict__ out) {
  int row = blockIdx.x;   // b*512 + t
  int b = row >> 9, t = row & 511;
  int lane = threadIdx.x;
  int qm = asgn[row] | padm[row];
  const float* sp = scores + (size_t)row * 512;
  float v[8];
  int mk[8];
#pragma unroll
  for (int m = 0; m < 8; ++m) {
    int a = lane + (m << 6);
    float val = 8.0f * tanhf(sp[a] * (1.0f / 16.0f));
    int masked = qm | fullm[b * CA + a];
    mk[m] = masked;
    v[m] = masked ? NEGV : val;
  }
  float mx = v[0];
#pragma unroll
  for (int m = 1; m < 8; ++m) mx = fmaxf(mx, v[m]);
#pragma unroll
  for (int off = 32; off >= 1; off >>= 1) mx = fmaxf(mx, __shfl_xor(mx, off));
  float sum = 0.f, e[8];
#pragma unroll
  for (int m = 0; m < 8; ++m) { e[m] = __expf(v[m] - mx); sum += e[m]; }
#pragma unroll
  for (int off = 32; off >= 1; off >>= 1) sum += __shfl_xor(sum, off);
  float inv = 1.0f / sum;
#pragma unroll
  for (int m = 0; m < 8; ++m) {
    int a = lane + (m << 6);
    float p = mk[m] ? 0.0f : e[m] * inv;
    out[(size_t)b * (CA * CT) + (size_t)a * CT + t] = p;   // (B,A,T)
  }
}

extern "C" void kernel_launch(void* const* d_in, const int* in_sizes, int n_in,
                              void* d_out, int out_size, void* d_ws, size_t ws_size,
                              hipStream_t stream) {
  const int* tasks = (const int*)d_in[0];
  const int* agents = (const int*)d_in[1];
  const int* indices = (const int*)d_in[2];
  const float* emb_t = (const float*)d_in[3];
  const float* emb_t_wo = (const float*)d_in[4];
  const float* emb_t_bo = (const float*)d_in[5];
  const float* emb_a = (const float*)d_in[6];
  const float* emb_a_wo = (const float*)d_in[7];
  const float* emb_a_bo = (const float*)d_in[8];
  const float* de_wq = (const float*)d_in[33];
  const float* de_wk = (const float*)d_in[34];
  const float* de_wv = (const float*)d_in[35];
  const float* de_wo = (const float*)d_in[36];
  const float* de_w1 = (const float*)d_in[37];
  const float* de_b1 = (const float*)d_in[38];
  const float* de_w2 = (const float*)d_in[39];
  const float* de_b2 = (const float*)d_in[40];
  const float* de_g1 = (const float*)d_in[41];
  const float* de_be1 = (const float*)d_in[42];
  const float* de_g2 = (const float*)d_in[43];
  const float* de_be2 = (const float*)d_in[44];
  const float* do_wq = (const float*)d_in[45];
  const float* do_wk = (const float*)d_in[46];

  float* ws = (float*)d_ws;
  float* ht = ws + 0;            // 4096x256
  float* ha = ws + 1048576;      // 4096x256
  float* qb = ws + 2097152;
  float* kb = ws + 3145728;
  float* vb = ws + 4194304;
  float* t1 = ws + 5242880;      // 4096x1024 (FFN mid / attn-out / scores)
  float* t2 = ws + 9437184;      // 4096x256
  int* asgn = (int*)(ws + 10485760);
  int* fullm = asgn + 4096;
  int* padm = asgn + 8192;

  mask_prep_kernel<<<16, 256, 0, stream>>>(tasks, indices, asgn, fullm, padm);
  mask_assign_kernel<<<128, 256, 0, stream>>>(indices, asgn);

  // embeddings
  embed_kernel<<<4096, 64, 0, stream>>>(tasks, emb_t, t2, 4);
  gemm_kernel<false, true, false><<<dim3(64, 4, 1), 256, 0, stream>>>(
      t2, emb_t_wo, emb_t_bo, ht, 4096, 256, 256, 0, 0, 0);
  embed_kernel<<<4096, 64, 0, stream>>>(agents, emb_a, t2, 2);
  gemm_kernel<false, true, false><<<dim3(64, 4, 1), 256, 0, stream>>>(
      t2, emb_a_wo, emb_a_bo, ha, 4096, 256, 256, 0, 0, 0);

  // two encoders, 3 layers each
  for (int enc = 0; enc < 2; ++enc) {
    float* x = enc ? ha : ht;
    int pb = enc ? 21 : 9;
    const float* wq = (const float*)d_in[pb + 0];
    const float* wk = (const float*)d_in[pb + 1];
    const float* wv = (const float*)d_in[pb + 2];
    const float* wo = (const float*)d_in[pb + 3];
    const float* w1 = (const float*)d_in[pb + 4];
    const float* b1 = (const float*)d_in[pb + 5];
    const float* w2 = (const float*)d_in[pb + 6];
    const float* b2 = (const float*)d_in[pb + 7];
    const float* g1 = (const float*)d_in[pb + 8];
    const float* be1 = (const float*)d_in[pb + 9];
    const float* g2 = (const float*)d_in[pb + 10];
    const float* be2 = (const float*)d_in[pb + 11];
    for (int l = 0; l < 3; ++l) {
      const float* wql = wq + l * 65536;
      const float* wkl = wk + l * 65536;
      const float* wvl = wv + l * 65536;
      const float* wol = wo + l * 65536;
      const float* w1l = w1 + l * 262144;
      const float* b1l = b1 + l * 1024;
      const float* w2l = w2 + l * 262144;
      const float* b2l = b2 + l * 256;
      gemm_kernel<false, false, false><<<dim3(64, 4, 1), 256, 0, stream>>>(
          x, wql, nullptr, qb, 4096, 256, 256, 0, 0, 0);
      gemm_kernel<false, false, false><<<dim3(64, 4, 1), 256, 0, stream>>>(
          x, wkl, nullptr, kb, 4096, 256, 256, 0, 0, 0);
      gemm_kernel<false, false, false><<<dim3(64, 4, 1), 256, 0, stream>>>(
          x, wvl, nullptr, vb, 4096, 256, 256, 0, 0, 0);
      attn_kernel<0><<<dim3(64, 8, 1), 256, 0, stream>>>(qb, kb, vb, t1, asgn, fullm, padm);
      gemm_kernel<false, false, false><<<dim3(64, 4, 1), 256, 0, stream>>>(
          t1, wol, nullptr, t2, 4096, 256, 256, 0, 0, 0);
      ln_add_kernel<<<4096, 64, 0, stream>>>(x, t2, g1 + l * 256, be1 + l * 256);
      gemm_kernel<false, true, true><<<dim3(64, 16, 1), 256, 0, stream>>>(
          x, w1l, b1l, t1, 4096, 1024, 256, 0, 0, 0);
      gemm_kernel<false, true, false><<<dim3(64, 4, 1), 256, 0, stream>>>(
          t1, w2l, b2l, t2, 4096, 256, 1024, 0, 0, 0);
      ln_add_kernel<<<4096, 64, 0, stream>>>(x, t2, g2 + l * 256, be2 + l * 256);
    }
  }

  // decoder cross-attention block (ht := h)
  gemm_kernel<false, false, false><<<dim3(64, 4, 1), 256, 0, stream>>>(
      ht, de_wq, nullptr, qb, 4096, 256, 256, 0, 0, 0);
  gemm_kernel<false, false, false><<<dim3(64, 4, 1), 256, 0, stream>>>(
      ha, de_wk, nullptr, kb, 4096, 256, 256, 0, 0, 0);
  gemm_kernel<false, false, false><<<dim3(64, 4, 1), 256, 0, stream>>>(
      ha, de_wv, nullptr, vb, 4096, 256, 256, 0, 0, 0);
  attn_kernel<1><<<dim3(64, 8, 1), 256, 0, stream>>>(qb, kb, vb, t1, asgn, fullm, padm);
  gemm_kernel<false, false, false><<<dim3(64, 4, 1), 256, 0, stream>>>(
      t1, de_wo, nullptr, t2, 4096, 256, 256, 0, 0, 0);
  ln_add_kernel<<<4096, 64, 0, stream>>>(ht, t2, de_g1, de_be1);
  gemm_kernel<false, true, true><<<dim3(64, 8, 1), 256, 0, stream>>>(
      ht, de_w1, de_b1, t1, 4096, 512, 256, 0, 0, 0);
  gemm_kernel<false, true, false><<<dim3(64, 4, 1), 256, 0, stream>>>(
      t1, de_w2, de_b2, t2, 4096, 256, 512, 0, 0, 0);
  ln_add_kernel<<<4096, 64, 0, stream>>>(ht, t2, de_g2, de_be2);

  // final scores + softmax + transpose
  gemm_kernel<false, false, false><<<dim3(64, 4, 1), 256, 0, stream>>>(
      ht, do_wq, nullptr, qb, 4096, 256, 256, 0, 0, 0);
  gemm_kernel<false, false, false><<<dim3(64, 4, 1), 256, 0, stream>>>(
      ha, do_wk, nullptr, kb, 4096, 256, 256, 0, 0, 0);
  gemm_kernel<true, false, false><<<dim3(8, 8, 8), 256, 0, stream>>>(
      qb, kb, nullptr, t1, 512, 512, 256, 131072, 131072, 262144);
  final_kernel<<<4096, 64, 0, stream>>>(t1, asgn, fullm, padm, (float*)d_out);
}

// Round 2
// 1458.609 us; speedup vs baseline: 1.7374x; 1.7374x over previous
//
#include <hip/hip_runtime.h>
#include <hip/hip_bf16.h>

// Transformer forward. bf16-MFMA GEMMs (f32 I/O), f32 attention.
// B=8 T=512 A=512 C=8 D=256 H=8 dh=32 FF=1024 DEC_FF=512 L=3
constexpr int CB = 8;
constexpr int CT = 512;
constexpr int CA = 512;
constexpr int CC = 8;
constexpr int CD = 256;
constexpr float NEGV = -1.0e9f;

typedef __attribute__((ext_vector_type(8))) short bf16x8;
typedef __attribute__((ext_vector_type(4))) float f32x4;

__device__ inline short f2bf(float f) {
  uint32_t u = __float_as_uint(f);
  uint32_t r = (u + 0x7FFFu + ((u >> 16) & 1u)) >> 16;
  return (short)r;
}

// ---------------- masks ----------------
__global__ void mask_prep_kernel(const int* __restrict__ tasks,
                                 const int* __restrict__ indices,
                                 int* __restrict__ asgn, int* __restrict__ fullm,
                                 int* __restrict__ padm) {
  int i = blockIdx.x * blockDim.x + threadIdx.x;
  if (i >= CB * CT) return;
  asgn[i] = 0;
  const int* tp = tasks + i * 4;
  padm[i] = (tp[0] == -1) && (tp[1] == -1) && (tp[2] == -1) && (tp[3] == -1);
  const int* ip = indices + i * CC;
  int full = 1;
#pragma unroll
  for (int c = 0; c < CC; ++c) full &= (ip[c] != -1);
  fullm[i] = full;
}

__global__ void mask_assign_kernel(const int* __restrict__ indices, int* __restrict__ asgn) {
  int i = blockIdx.x * blockDim.x + threadIdx.x;
  if (i >= CB * CA * CC) return;
  int b = i / (CA * CC);
  int idx = indices[i];
  if (idx >= 0) asgn[b * CT + idx] = 1;   // benign race: same value
}

// ---------------- embedding gather+sum ----------------
__global__ void embed_kernel(const int* __restrict__ toks, const float* __restrict__ table,
                             float* __restrict__ out, int nf) {
  int row = blockIdx.x;
  int lane = threadIdx.x;
  const int* tp = toks + row * nf;
  float4 acc = make_float4(0.f, 0.f, 0.f, 0.f);
  for (int f = 0; f < nf; ++f) {
    int t = 1 + tp[f];
    float4 v = *(const float4*)(table + ((size_t)f * 33 + t) * CD + lane * 4);
    acc.x += v.x; acc.y += v.y; acc.z += v.z; acc.w += v.w;
  }
  *(float4*)(out + (size_t)row * CD + lane * 4) = acc;
}

// ---------------- residual add + LayerNorm (in place on x) ----------------
__global__ void ln_add_kernel(float* __restrict__ x, const float* __restrict__ res,
                              const float* __restrict__ g, const float* __restrict__ b) {
  int row = blockIdx.x;
  int lane = threadIdx.x;
  float4 xv = *(const float4*)(x + (size_t)row * CD + lane * 4);
  float4 rv = *(const float4*)(res + (size_t)row * CD + lane * 4);
  float v0 = xv.x + rv.x, v1 = xv.y + rv.y, v2 = xv.z + rv.z, v3 = xv.w + rv.w;
  float s = v0 + v1 + v2 + v3;
  float s2 = v0 * v0 + v1 * v1 + v2 * v2 + v3 * v3;
#pragma unroll
  for (int off = 32; off >= 1; off >>= 1) {
    s += __shfl_xor(s, off);
    s2 += __shfl_xor(s2, off);
  }
  float mean = s * (1.0f / CD);
  float var = s2 * (1.0f / CD) - mean * mean;
  float rstd = rsqrtf(var + 1e-5f);
  float4 gv = *(const float4*)(g + lane * 4);
  float4 bv = *(const float4*)(b + lane * 4);
  float4 o;
  o.x = (v0 - mean) * rstd * gv.x + bv.x;
  o.y = (v1 - mean) * rstd * gv.y + bv.y;
  o.z = (v2 - mean) * rstd * gv.z + bv.z;
  o.w = (v3 - mean) * rstd * gv.w + bv.w;
  *(float4*)(x + (size_t)row * CD + lane * 4) = o;
}

// ---------------- bf16 MFMA GEMM: C = A @ B (+bias)(+relu), f32 I/O ----------------
// Tile 64x64, BK=64, 256 threads = 4 waves (2x2 layout, 32x32 per wave).
// A: [M][K] f32.  B: [K][N] f32 (TRANSB=false) or [N][K] f32 (TRANSB=true).
template <bool TRANSB, bool BIAS, bool RELU>
__global__ __launch_bounds__(256) void mgemm_kernel(
    const float* __restrict__ A, const float* __restrict__ Bm,
    const float* __restrict__ bias, float* __restrict__ C,
    int Ndim, int Kdim, long long sA, long long sB, long long sC) {
  __shared__ short As[64][72];   // [m][k], 72-short stride (144 B, 16B-aligned)
  __shared__ short Bs[64][72];   // [n][k]
  const float* Ab = A + (size_t)blockIdx.z * sA;
  const float* Bb = Bm + (size_t)blockIdx.z * sB;
  float* Cb = C + (size_t)blockIdx.z * sC;
  const int bm = blockIdx.x * 64, bn = blockIdx.y * 64;
  const int t = threadIdx.x;
  const int lane = t & 63, wave = t >> 6;
  const int wm = (wave >> 1) * 32, wn = (wave & 1) * 32;
  const int fr = lane & 15, fs = lane >> 4;   // fragment row/col index, k-slot

  f32x4 acc[2][2] = {};

  for (int k0 = 0; k0 < Kdim; k0 += 64) {
    // stage A: 64 rows x 64 k, 8 consecutive floats per thread-group
#pragma unroll
    for (int rep = 0; rep < 2; ++rep) {
      int g = rep * 256 + t;
      int row = g >> 3, k8 = (g & 7) * 8;
      const float* src = Ab + (size_t)(bm + row) * Kdim + k0 + k8;
      float4 u0 = *(const float4*)src;
      float4 u1 = *(const float4*)(src + 4);
      bf16x8 h;
      h[0] = f2bf(u0.x); h[1] = f2bf(u0.y); h[2] = f2bf(u0.z); h[3] = f2bf(u0.w);
      h[4] = f2bf(u1.x); h[5] = f2bf(u1.y); h[6] = f2bf(u1.z); h[7] = f2bf(u1.w);
      *(bf16x8*)&As[row][k8] = h;
    }
    // stage B -> LDS [n][k]
    if (TRANSB) {
#pragma unroll
      for (int rep = 0; rep < 2; ++rep) {
        int g = rep * 256 + t;
        int n = g >> 3, k8 = (g & 7) * 8;
        const float* src = Bb + (size_t)(bn + n) * Kdim + k0 + k8;
        float4 u0 = *(const float4*)src;
        float4 u1 = *(const float4*)(src + 4);
        bf16x8 h;
        h[0] = f2bf(u0.x); h[1] = f2bf(u0.y); h[2] = f2bf(u0.z); h[3] = f2bf(u0.w);
        h[4] = f2bf(u1.x); h[5] = f2bf(u1.y); h[6] = f2bf(u1.z); h[7] = f2bf(u1.w);
        *(bf16x8*)&Bs[n][k8] = h;
      }
    } else {
      int n = t & 63;
#pragma unroll
      for (int rep = 0; rep < 2; ++rep) {
        int kc = (t >> 6) + rep * 4;   // 8-k chunk id
        bf16x8 h;
#pragma unroll
        for (int j = 0; j < 8; ++j)
          h[j] = f2bf(Bb[(size_t)(k0 + kc * 8 + j) * Ndim + bn + n]);
        *(bf16x8*)&Bs[n][kc * 8] = h;
      }
    }
    __syncthreads();
#pragma unroll
    for (int kk = 0; kk < 2; ++kk) {
      bf16x8 a0 = *(bf16x8*)&As[wm + fr][kk * 32 + fs * 8];
      bf16x8 a1 = *(bf16x8*)&As[wm + 16 + fr][kk * 32 + fs * 8];
      bf16x8 b0 = *(bf16x8*)&Bs[wn + fr][kk * 32 + fs * 8];
      bf16x8 b1 = *(bf16x8*)&Bs[wn + 16 + fr][kk * 32 + fs * 8];
      acc[0][0] = __builtin_amdgcn_mfma_f32_16x16x32_bf16(a0, b0, acc[0][0], 0, 0, 0);
      acc[0][1] = __builtin_amdgcn_mfma_f32_16x16x32_bf16(a0, b1, acc[0][1], 0, 0, 0);
      acc[1][0] = __builtin_amdgcn_mfma_f32_16x16x32_bf16(a1, b0, acc[1][0], 0, 0, 0);
      acc[1][1] = __builtin_amdgcn_mfma_f32_16x16x32_bf16(a1, b1, acc[1][1], 0, 0, 0);
    }
    __syncthreads();
  }

  // epilogue: C/D layout col=lane&15, row=(lane>>4)*4+reg
#pragma unroll
  for (int fi = 0; fi < 2; ++fi)
#pragma unroll
    for (int fj = 0; fj < 2; ++fj) {
      int row0 = bm + wm + fi * 16 + fs * 4;
      int col = bn + wn + fj * 16 + fr;
      float bv = BIAS ? bias[col] : 0.0f;
#pragma unroll
      for (int r = 0; r < 4; ++r) {
        float v = acc[fi][fj][r] + bv;
        if (RELU) v = fmaxf(v, 0.0f);
        Cb[(size_t)(row0 + r) * Ndim + col] = v;
      }
    }
}

// ---------------- attention over flat-chunk heads (f32, 8 waves) ----------------
template <int MODE>
__global__ __launch_bounds__(512) void attn_kernel(
    const float* __restrict__ qb, const float* __restrict__ kb, const float* __restrict__ vb,
    float* __restrict__ ob,
    const int* __restrict__ asgn, const int* __restrict__ fullm, const int* __restrict__ padm) {
  __shared__ float Ks[512 * 36];   // stride 36 breaks bank conflicts
  __shared__ float Vs[512 * 32];
  __shared__ float Ps[8][512];
  const int bh = blockIdx.x;
  const int b = bh >> 3;
  const size_t base = (size_t)bh * (512 * 32);
  const int tid = threadIdx.x;
  for (int i = tid; i < 4096; i += 512) {
    int x = i >> 3, g = (i & 7) << 2;
    *(float4*)&Ks[x * 36 + g] = *(const float4*)(kb + base + x * 32 + g);
    *(float4*)&Vs[x * 32 + g] = *(const float4*)(vb + base + x * 32 + g);
  }
  __syncthreads();
  const int wave = tid >> 6, lane = tid & 63;
  float* Pw = Ps[wave];
  const int q0 = blockIdx.y * 128 + wave * 16;
  int kmask[8];
#pragma unroll
  for (int m = 0; m < 8; ++m) {
    int kx = lane + (m << 6);
    kmask[m] = (MODE == 0) ? padm[b * CT + kx] : fullm[b * CA + kx];
  }
  for (int qi = 0; qi < 16; ++qi) {
    const int qx = q0 + qi;
    const float* Qr = qb + base + qx * 32;
    float qreg[32];
#pragma unroll
    for (int g = 0; g < 8; ++g) {
      float4 t4 = *(const float4*)(Qr + g * 4);
      qreg[g * 4 + 0] = t4.x; qreg[g * 4 + 1] = t4.y;
      qreg[g * 4 + 2] = t4.z; qreg[g * 4 + 3] = t4.w;
    }
    int qmask = 0;
    if (MODE == 1) qmask = asgn[b * CT + qx] | padm[b * CT + qx];
    float s[8];
    int mk[8];
#pragma unroll
    for (int m = 0; m < 8; ++m) {
      int kx = lane + (m << 6);
      const float* Kr = &Ks[kx * 36];
      float acc = 0.f;
#pragma unroll
      for (int g = 0; g < 8; ++g) {
        float4 k4 = *(const float4*)(Kr + g * 4);
        acc = fmaf(qreg[g * 4 + 0], k4.x, acc);
        acc = fmaf(qreg[g * 4 + 1], k4.y, acc);
        acc = fmaf(qreg[g * 4 + 2], k4.z, acc);
        acc = fmaf(qreg[g * 4 + 3], k4.w, acc);
      }
      acc *= 0.17677669529663687f;   // 1/sqrt(32)
      int masked = (MODE == 1) ? (qmask | kmask[m]) : kmask[m];
      mk[m] = masked;
      s[m] = masked ? NEGV : acc;
    }
    float mx = s[0];
#pragma unroll
    for (int m = 1; m < 8; ++m) mx = fmaxf(mx, s[m]);
#pragma unroll
    for (int off = 32; off >= 1; off >>= 1) mx = fmaxf(mx, __shfl_xor(mx, off));
    float sum = 0.f, e[8];
#pragma unroll
    for (int m = 0; m < 8; ++m) { e[m] = __expf(s[m] - mx); sum += e[m]; }
#pragma unroll
    for (int off = 32; off >= 1; off >>= 1) sum += __shfl_xor(sum, off);
    float inv = 1.0f / sum;
#pragma unroll
    for (int m = 0; m < 8; ++m) Pw[lane + (m << 6)] = mk[m] ? 0.0f : e[m] * inv;
    __syncthreads();
    const int j = lane & 31, half = lane >> 5;
    const int x0 = half << 8;
    float oacc = 0.f;
    for (int xx4 = 0; xx4 < 64; ++xx4) {
      float4 p4 = *(const float4*)&Pw[x0 + (xx4 << 2)];
      const float* Vp = &Vs[(x0 + (xx4 << 2)) * 32 + j];
      oacc = fmaf(p4.x, Vp[0], oacc);
      oacc = fmaf(p4.y, Vp[32], oacc);
      oacc = fmaf(p4.z, Vp[64], oacc);
      oacc = fmaf(p4.w, Vp[96], oacc);
    }
    oacc += __shfl_xor(oacc, 32);
    if (lane < 32) ob[base + qx * 32 + j] = oacc;
    __syncthreads();
  }
}

// ---------------- final: 8*tanh(scores/16), mask, softmax over a, write transposed ----------------
__global__ void final_kernel(const float* __restrict__ scores,
                             const int* __restrict__ asgn, const int* __restrict__ fullm,
                             const int* __restrict__ padm, float* __restrict__ out) {
  int row = blockIdx.x;   // b*512 + t
  int b = row >> 9, t = row & 511;
  int lane = threadIdx.x;
  int qm = asgn[row] | padm[row];
  const float* sp = scores + (size_t)row * 512;
  float v[8];
  int mk[8];
#pragma unroll
  for (int m = 0; m < 8; ++m) {
    int a = lane + (m << 6);
    float val = 8.0f * tanhf(sp[a] * (1.0f / 16.0f));
    int masked = qm | fullm[b * CA + a];
    mk[m] = masked;
    v[m] = masked ? NEGV : val;
  }
  float mx = v[0];
#pragma unroll
  for (int m = 1; m < 8; ++m) mx = fmaxf(mx, v[m]);
#pragma unroll
  for (int off = 32; off >= 1; off >>= 1) mx = fmaxf(mx, __shfl_xor(mx, off));
  float sum = 0.f, e[8];
#pragma unroll
  for (int m = 0; m < 8; ++m) { e[m] = __expf(v[m] - mx); sum += e[m]; }
#pragma unroll
  for (int off = 32; off >= 1; off >>= 1) sum += __shfl_xor(sum, off);
  float inv = 1.0f / sum;
#pragma unroll
  for (int m = 0; m < 8; ++m) {
    int a = lane + (m << 6);
    float p = mk[m] ? 0.0f : e[m] * inv;
    out[(size_t)b * (CA * CT) + (size_t)a * CT + t] = p;   // (B,A,T)
  }
}

extern "C" void kernel_launch(void* const* d_in, const int* in_sizes, int n_in,
                              void* d_out, int out_size, void* d_ws, size_t ws_size,
                              hipStream_t stream) {
  const int* tasks = (const int*)d_in[0];
  const int* agents = (const int*)d_in[1];
  const int* indices = (const int*)d_in[2];
  const float* emb_t = (const float*)d_in[3];
  const float* emb_t_wo = (const float*)d_in[4];
  const float* emb_t_bo = (const float*)d_in[5];
  const float* emb_a = (const float*)d_in[6];
  const float* emb_a_wo = (const float*)d_in[7];
  const float* emb_a_bo = (const float*)d_in[8];
  const float* de_wq = (const float*)d_in[33];
  const float* de_wk = (const float*)d_in[34];
  const float* de_wv = (const float*)d_in[35];
  const float* de_wo = (const float*)d_in[36];
  const float* de_w1 = (const float*)d_in[37];
  const float* de_b1 = (const float*)d_in[38];
  const float* de_w2 = (const float*)d_in[39];
  const float* de_b2 = (const float*)d_in[40];
  const float* de_g1 = (const float*)d_in[41];
  const float* de_be1 = (const float*)d_in[42];
  const float* de_g2 = (const float*)d_in[43];
  const float* de_be2 = (const float*)d_in[44];
  const float* do_wq = (const float*)d_in[45];
  const float* do_wk = (const float*)d_in[46];

  float* ws = (float*)d_ws;
  float* ht = ws + 0;            // 4096x256
  float* ha = ws + 1048576;      // 4096x256
  float* qb = ws + 2097152;
  float* kb = ws + 3145728;
  float* vb = ws + 4194304;
  float* t1 = ws + 5242880;      // 4096x1024 (FFN mid / attn-out / scores)
  float* t2 = ws + 9437184;      // 4096x256
  int* asgn = (int*)(ws + 10485760);
  int* fullm = asgn + 4096;
  int* padm = asgn + 8192;

  mask_prep_kernel<<<16, 256, 0, stream>>>(tasks, indices, asgn, fullm, padm);
  mask_assign_kernel<<<128, 256, 0, stream>>>(indices, asgn);

  // embeddings
  embed_kernel<<<4096, 64, 0, stream>>>(tasks, emb_t, t2, 4);
  mgemm_kernel<false, true, false><<<dim3(64, 4, 1), 256, 0, stream>>>(
      t2, emb_t_wo, emb_t_bo, ht, 256, 256, 0, 0, 0);
  embed_kernel<<<4096, 64, 0, stream>>>(agents, emb_a, t2, 2);
  mgemm_kernel<false, true, false><<<dim3(64, 4, 1), 256, 0, stream>>>(
      t2, emb_a_wo, emb_a_bo, ha, 256, 256, 0, 0, 0);

  // two encoders, 3 layers each
  for (int enc = 0; enc < 2; ++enc) {
    float* x = enc ? ha : ht;
    int pb = enc ? 21 : 9;
    const float* wq = (const float*)d_in[pb + 0];
    const float* wk = (const float*)d_in[pb + 1];
    const float* wv = (const float*)d_in[pb + 2];
    const float* wo = (const float*)d_in[pb + 3];
    const float* w1 = (const float*)d_in[pb + 4];
    const float* b1 = (const float*)d_in[pb + 5];
    const float* w2 = (const float*)d_in[pb + 6];
    const float* b2 = (const float*)d_in[pb + 7];
    const float* g1 = (const float*)d_in[pb + 8];
    const float* be1 = (const float*)d_in[pb + 9];
    const float* g2 = (const float*)d_in[pb + 10];
    const float* be2 = (const float*)d_in[pb + 11];
    for (int l = 0; l < 3; ++l) {
      const float* wql = wq + l * 65536;
      const float* wkl = wk + l * 65536;
      const float* wvl = wv + l * 65536;
      const float* wol = wo + l * 65536;
      const float* w1l = w1 + l * 262144;
      const float* b1l = b1 + l * 1024;
      const float* w2l = w2 + l * 262144;
      const float* b2l = b2 + l * 256;
      mgemm_kernel<false, false, false><<<dim3(64, 4, 1), 256, 0, stream>>>(
          x, wql, nullptr, qb, 256, 256, 0, 0, 0);
      mgemm_kernel<false, false, false><<<dim3(64, 4, 1), 256, 0, stream>>>(
          x, wkl, nullptr, kb, 256, 256, 0, 0, 0);
      mgemm_kernel<false, false, false><<<dim3(64, 4, 1), 256, 0, stream>>>(
          x, wvl, nullptr, vb, 256, 256, 0, 0, 0);
      attn_kernel<0><<<dim3(64, 4, 1), 512, 0, stream>>>(qb, kb, vb, t1, asgn, fullm, padm);
      mgemm_kernel<false, false, false><<<dim3(64, 4, 1), 256, 0, stream>>>(
          t1, wol, nullptr, t2, 256, 256, 0, 0, 0);
      ln_add_kernel<<<4096, 64, 0, stream>>>(x, t2, g1 + l * 256, be1 + l * 256);
      mgemm_kernel<false, true, true><<<dim3(64, 16, 1), 256, 0, stream>>>(
          x, w1l, b1l, t1, 1024, 256, 0, 0, 0);
      mgemm_kernel<false, true, false><<<dim3(64, 4, 1), 256, 0, stream>>>(
          t1, w2l, b2l, t2, 256, 1024, 0, 0, 0);
      ln_add_kernel<<<4096, 64, 0, stream>>>(x, t2, g2 + l * 256, be2 + l * 256);
    }
  }

  // decoder cross-attention block (ht := h)
  mgemm_kernel<false, false, false><<<dim3(64, 4, 1), 256, 0, stream>>>(
      ht, de_wq, nullptr, qb, 256, 256, 0, 0, 0);
  mgemm_kernel<false, false, false><<<dim3(64, 4, 1), 256, 0, stream>>>(
      ha, de_wk, nullptr, kb, 256, 256, 0, 0, 0);
  mgemm_kernel<false, false, false><<<dim3(64, 4, 1), 256, 0, stream>>>(
      ha, de_wv, nullptr, vb, 256, 256, 0, 0, 0);
  attn_kernel<1><<<dim3(64, 4, 1), 512, 0, stream>>>(qb, kb, vb, t1, asgn, fullm, padm);
  mgemm_kernel<false, false, false><<<dim3(64, 4, 1), 256, 0, stream>>>(
      t1, de_wo, nullptr, t2, 256, 256, 0, 0, 0);
  ln_add_kernel<<<4096, 64, 0, stream>>>(ht, t2, de_g1, de_be1);
  mgemm_kernel<false, true, true><<<dim3(64, 8, 1), 256, 0, stream>>>(
      ht, de_w1, de_b1, t1, 512, 256, 0, 0, 0);
  mgemm_kernel<false, true, false><<<dim3(64, 4, 1), 256, 0, stream>>>(
      t1, de_w2, de_b2, t2, 256, 512, 0, 0, 0);
  ln_add_kernel<<<4096, 64, 0, stream>>>(ht, t2, de_g2, de_be2);

  // final scores + softmax + transpose
  mgemm_kernel<false, false, false><<<dim3(64, 4, 1), 256, 0, stream>>>(
      ht, do_wq, nullptr, qb, 256, 256, 0, 0, 0);
  mgemm_kernel<false, false, false><<<dim3(64, 4, 1), 256, 0, stream>>>(
      ha, do_wk, nullptr, kb, 256, 256, 0, 0, 0);
  mgemm_kernel<true, false, false><<<dim3(8, 8, 8), 256, 0, stream>>>(
      qb, kb, nullptr, t1, 512, 256, 131072, 131072, 262144);
  final_kernel<<<4096, 64, 0, stream>>>(t1, asgn, fullm, padm, (float*)d_out);
}

// Round 3
// 772.301 us; speedup vs baseline: 3.2813x; 1.8887x over previous
//
#include <hip/hip_runtime.h>
#include <hip/hip_bf16.h>

// Transformer forward. bf16-MFMA GEMMs + bf16-MFMA flash attention, f32 I/O.
// B=8 T=512 A=512 C=8 D=256 H=8 dh=32 FF=1024 DEC_FF=512 L=3
constexpr int CB = 8;
constexpr int CT = 512;
constexpr int CA = 512;
constexpr int CC = 8;
constexpr int CD = 256;
constexpr float NEGV = -1.0e9f;

typedef __attribute__((ext_vector_type(8))) short bf16x8;
typedef __attribute__((ext_vector_type(4))) float f32x4;

__device__ inline short f2bf(float f) {
  uint32_t u = __float_as_uint(f);
  uint32_t r = (u + 0x7FFFu + ((u >> 16) & 1u)) >> 16;
  return (short)r;
}

// ---------------- masks ----------------
__global__ void mask_prep_kernel(const int* __restrict__ tasks,
                                 const int* __restrict__ indices,
                                 int* __restrict__ asgn, int* __restrict__ fullm,
                                 int* __restrict__ padm) {
  int i = blockIdx.x * blockDim.x + threadIdx.x;
  if (i >= CB * CT) return;
  asgn[i] = 0;
  const int* tp = tasks + i * 4;
  padm[i] = (tp[0] == -1) && (tp[1] == -1) && (tp[2] == -1) && (tp[3] == -1);
  const int* ip = indices + i * CC;
  int full = 1;
#pragma unroll
  for (int c = 0; c < CC; ++c) full &= (ip[c] != -1);
  fullm[i] = full;
}

__global__ void mask_assign_kernel(const int* __restrict__ indices, int* __restrict__ asgn) {
  int i = blockIdx.x * blockDim.x + threadIdx.x;
  if (i >= CB * CA * CC) return;
  int b = i / (CA * CC);
  int idx = indices[i];
  if (idx >= 0) asgn[b * CT + idx] = 1;   // benign race: same value
}

// ---------------- embedding gather+sum ----------------
__global__ void embed_kernel(const int* __restrict__ toks, const float* __restrict__ table,
                             float* __restrict__ out, int nf) {
  int row = blockIdx.x;
  int lane = threadIdx.x;
  const int* tp = toks + row * nf;
  float4 acc = make_float4(0.f, 0.f, 0.f, 0.f);
  for (int f = 0; f < nf; ++f) {
    int t = 1 + tp[f];
    float4 v = *(const float4*)(table + ((size_t)f * 33 + t) * CD + lane * 4);
    acc.x += v.x; acc.y += v.y; acc.z += v.z; acc.w += v.w;
  }
  *(float4*)(out + (size_t)row * CD + lane * 4) = acc;
}

// ---------------- residual add + LayerNorm (in place on x) ----------------
__global__ void ln_add_kernel(float* __restrict__ x, const float* __restrict__ res,
                              const float* __restrict__ g, const float* __restrict__ b) {
  int row = blockIdx.x;
  int lane = threadIdx.x;
  float4 xv = *(const float4*)(x + (size_t)row * CD + lane * 4);
  float4 rv = *(const float4*)(res + (size_t)row * CD + lane * 4);
  float v0 = xv.x + rv.x, v1 = xv.y + rv.y, v2 = xv.z + rv.z, v3 = xv.w + rv.w;
  float s = v0 + v1 + v2 + v3;
  float s2 = v0 * v0 + v1 * v1 + v2 * v2 + v3 * v3;
#pragma unroll
  for (int off = 32; off >= 1; off >>= 1) {
    s += __shfl_xor(s, off);
    s2 += __shfl_xor(s2, off);
  }
  float mean = s * (1.0f / CD);
  float var = s2 * (1.0f / CD) - mean * mean;
  float rstd = rsqrtf(var + 1e-5f);
  float4 gv = *(const float4*)(g + lane * 4);
  float4 bv = *(const float4*)(b + lane * 4);
  float4 o;
  o.x = (v0 - mean) * rstd * gv.x + bv.x;
  o.y = (v1 - mean) * rstd * gv.y + bv.y;
  o.z = (v2 - mean) * rstd * gv.z + bv.z;
  o.w = (v3 - mean) * rstd * gv.w + bv.w;
  *(float4*)(x + (size_t)row * CD + lane * 4) = o;
}

// ---------------- bf16 MFMA GEMM body: C = A @ B (+bias)(+relu), f32 I/O ----------------
// Tile 64x64, BK=64, 256 threads = 4 waves (2x2 layout, 32x32 per wave).
template <bool TRANSB, bool BIAS, bool RELU>
__device__ __forceinline__ void gemm_body(
    const float* __restrict__ Ab, const float* __restrict__ Bb,
    const float* __restrict__ bias, float* __restrict__ Cb,
    int Ndim, int Kdim, int bm, int bn) {
  __shared__ short As[64][72];   // [m][k], 144 B stride (16B-aligned)
  __shared__ short Bs[64][72];   // [n][k]
  const int t = threadIdx.x;
  const int lane = t & 63, wave = t >> 6;
  const int wm = (wave >> 1) * 32, wn = (wave & 1) * 32;
  const int fr = lane & 15, fs = lane >> 4;

  f32x4 acc[2][2] = {};

  for (int k0 = 0; k0 < Kdim; k0 += 64) {
#pragma unroll
    for (int rep = 0; rep < 2; ++rep) {
      int g = rep * 256 + t;
      int row = g >> 3, k8 = (g & 7) * 8;
      const float* src = Ab + (size_t)(bm + row) * Kdim + k0 + k8;
      float4 u0 = *(const float4*)src;
      float4 u1 = *(const float4*)(src + 4);
      bf16x8 h;
      h[0] = f2bf(u0.x); h[1] = f2bf(u0.y); h[2] = f2bf(u0.z); h[3] = f2bf(u0.w);
      h[4] = f2bf(u1.x); h[5] = f2bf(u1.y); h[6] = f2bf(u1.z); h[7] = f2bf(u1.w);
      *(bf16x8*)&As[row][k8] = h;
    }
    if (TRANSB) {
#pragma unroll
      for (int rep = 0; rep < 2; ++rep) {
        int g = rep * 256 + t;
        int n = g >> 3, k8 = (g & 7) * 8;
        const float* src = Bb + (size_t)(bn + n) * Kdim + k0 + k8;
        float4 u0 = *(const float4*)src;
        float4 u1 = *(const float4*)(src + 4);
        bf16x8 h;
        h[0] = f2bf(u0.x); h[1] = f2bf(u0.y); h[2] = f2bf(u0.z); h[3] = f2bf(u0.w);
        h[4] = f2bf(u1.x); h[5] = f2bf(u1.y); h[6] = f2bf(u1.z); h[7] = f2bf(u1.w);
        *(bf16x8*)&Bs[n][k8] = h;
      }
    } else {
      int n = t & 63;
#pragma unroll
      for (int rep = 0; rep < 2; ++rep) {
        int kc = (t >> 6) + rep * 4;
        bf16x8 h;
#pragma unroll
        for (int j = 0; j < 8; ++j)
          h[j] = f2bf(Bb[(size_t)(k0 + kc * 8 + j) * Ndim + bn + n]);
        *(bf16x8*)&Bs[n][kc * 8] = h;
      }
    }
    __syncthreads();
#pragma unroll
    for (int kk = 0; kk < 2; ++kk) {
      bf16x8 a0 = *(bf16x8*)&As[wm + fr][kk * 32 + fs * 8];
      bf16x8 a1 = *(bf16x8*)&As[wm + 16 + fr][kk * 32 + fs * 8];
      bf16x8 b0 = *(bf16x8*)&Bs[wn + fr][kk * 32 + fs * 8];
      bf16x8 b1 = *(bf16x8*)&Bs[wn + 16 + fr][kk * 32 + fs * 8];
      acc[0][0] = __builtin_amdgcn_mfma_f32_16x16x32_bf16(a0, b0, acc[0][0], 0, 0, 0);
      acc[0][1] = __builtin_amdgcn_mfma_f32_16x16x32_bf16(a0, b1, acc[0][1], 0, 0, 0);
      acc[1][0] = __builtin_amdgcn_mfma_f32_16x16x32_bf16(a1, b0, acc[1][0], 0, 0, 0);
      acc[1][1] = __builtin_amdgcn_mfma_f32_16x16x32_bf16(a1, b1, acc[1][1], 0, 0, 0);
    }
    __syncthreads();
  }

#pragma unroll
  for (int fi = 0; fi < 2; ++fi)
#pragma unroll
    for (int fj = 0; fj < 2; ++fj) {
      int row0 = bm + wm + fi * 16 + fs * 4;
      int col = bn + wn + fj * 16 + fr;
      float bv = BIAS ? bias[col] : 0.0f;
#pragma unroll
      for (int r = 0; r < 4; ++r) {
        float v = acc[fi][fj][r] + bv;
        if (RELU) v = fmaxf(v, 0.0f);
        Cb[(size_t)(row0 + r) * Ndim + col] = v;
      }
    }
}

template <bool TRANSB, bool BIAS, bool RELU>
__global__ __launch_bounds__(256) void mgemm_kernel(
    const float* __restrict__ A, const float* __restrict__ Bm,
    const float* __restrict__ bias, float* __restrict__ C,
    int Ndim, int Kdim, long long sA, long long sB, long long sC) {
  gemm_body<TRANSB, BIAS, RELU>(A + (size_t)blockIdx.z * sA, Bm + (size_t)blockIdx.z * sB,
                                bias, C + (size_t)blockIdx.z * sC,
                                Ndim, Kdim, blockIdx.x * 64, blockIdx.y * 64);
}

// fused multi-weight GEMM: blockIdx.z selects B pointer and C = Cbase + z*strideC
__global__ __launch_bounds__(256) void mgemm_multi_kernel(
    const float* __restrict__ A, const float* __restrict__ B0,
    const float* __restrict__ B1, const float* __restrict__ B2,
    float* __restrict__ C, int Ndim, int Kdim, long long strideC) {
  const float* Bb = (blockIdx.z == 0) ? B0 : (blockIdx.z == 1) ? B1 : B2;
  gemm_body<false, false, false>(A, Bb, nullptr, C + (size_t)blockIdx.z * strideC,
                                 Ndim, Kdim, blockIdx.x * 64, blockIdx.y * 64);
}

// ---------------- MFMA flash attention over flat-chunk heads ----------------
// q/k/v/o: flat (B*T*D); head (b,h) rows are 32-float chunks at (b*8+h)*16384 + x*32.
// MODE 0: encoder self-attn, key mask padm[b,k]. MODE 1: decoder, q-mask asgn|padm, key mask fullm.
// Block: 512 threads = 8 waves; wave handles 16 queries; grid (64, 4).
template <int MODE>
__global__ __launch_bounds__(512) void mattn_kernel(
    const float* __restrict__ qb, const float* __restrict__ kb, const float* __restrict__ vb,
    float* __restrict__ ob,
    const int* __restrict__ asgn, const int* __restrict__ fullm, const int* __restrict__ padm) {
  __shared__ short Ks[512][40];        // [key][d], 80B stride
  __shared__ short Vt[32][520];        // [d][key], 1040B stride
  __shared__ short Pb[8][16][40];      // per-wave P bounce [q][key-in-chunk]
  __shared__ unsigned int mwords[16];  // key-mask bits: mwords[c] bit tl = mask[tl*16+c]
  const int bh = blockIdx.x;
  const int b = bh >> 3;
  const size_t base = (size_t)bh * (512 * 32);
  const int tid = threadIdx.x;

  // stage K (bf16)
#pragma unroll
  for (int r = 0; r < 4; ++r) {
    int i = r * 512 + tid;
    int row = i >> 2, seg = (i & 3) * 8;
    const float* src = kb + base + row * 32 + seg;
    float4 u0 = *(const float4*)src, u1 = *(const float4*)(src + 4);
    bf16x8 h;
    h[0] = f2bf(u0.x); h[1] = f2bf(u0.y); h[2] = f2bf(u0.z); h[3] = f2bf(u0.w);
    h[4] = f2bf(u1.x); h[5] = f2bf(u1.y); h[6] = f2bf(u1.z); h[7] = f2bf(u1.w);
    *(bf16x8*)&Ks[row][seg] = h;
  }
  // stage V transposed (bf16): thread owns dim d = tid&31, 4-key groups
  {
    int d = tid & 31, g = tid >> 5;   // g in 0..15
#pragma unroll
    for (int r = 0; r < 8; ++r) {
      int key0 = (r * 16 + g) * 4;
      const float* vp = vb + base + (size_t)key0 * 32 + d;
      short p0 = f2bf(vp[0]);
      short p1 = f2bf(vp[32]);
      short p2 = f2bf(vp[64]);
      short p3 = f2bf(vp[96]);
      int lo = ((int)(unsigned short)p0) | (((int)(unsigned short)p1) << 16);
      int hi = ((int)(unsigned short)p2) | (((int)(unsigned short)p3) << 16);
      *(int2*)&Vt[d][key0] = make_int2(lo, hi);
    }
  }
  // key-mask words
  if (tid < 16) {
    unsigned w = 0;
    for (int tl = 0; tl < 32; ++tl) {
      int key = tl * 16 + tid;
      int m = (MODE == 0) ? padm[b * CT + key] : fullm[b * CA + key];
      w |= ((unsigned)(m != 0)) << tl;
    }
    mwords[tid] = w;
  }
  __syncthreads();

  const int wave = tid >> 6, lane = tid & 63;
  const int fr = lane & 15, fs = lane >> 4;
  const int q0 = blockIdx.y * 128 + wave * 16;
  const int q = q0 + fr;

  // Q fragment (B operand): Q[q=fr][d = fs*8+j], scaled by 1/sqrt(32)
  const float sc = 0.17677669529663687f;
  const float* Qr = qb + base + (size_t)q * 32 + fs * 8;
  float4 u0 = *(const float4*)Qr, u1 = *(const float4*)(Qr + 4);
  bf16x8 qf;
  qf[0] = f2bf(u0.x * sc); qf[1] = f2bf(u0.y * sc);
  qf[2] = f2bf(u0.z * sc); qf[3] = f2bf(u0.w * sc);
  qf[4] = f2bf(u1.x * sc); qf[5] = f2bf(u1.y * sc);
  qf[6] = f2bf(u1.z * sc); qf[7] = f2bf(u1.w * sc);

  unsigned qmbits = 0;
  if (MODE == 1) {
    int qm = asgn[b * CT + q] | padm[b * CT + q];
    qmbits = qm ? 0xFFFFFFFFu : 0u;
  }
  unsigned mw[4];
#pragma unroll
  for (int g = 0; g < 4; ++g) mw[g] = mwords[4 * fs + g] | qmbits;

  // pass 1: S^T tiles = mfma(K_tile, Q): lane holds S[key = tl*16 + fs*4+reg][q = fr]
  f32x4 s[32];
#pragma unroll
  for (int tl = 0; tl < 32; ++tl) {
    bf16x8 kf = *(bf16x8*)&Ks[tl * 16 + fr][fs * 8];
    f32x4 z = {0.f, 0.f, 0.f, 0.f};
    s[tl] = __builtin_amdgcn_mfma_f32_16x16x32_bf16(kf, qf, z, 0, 0, 0);
  }
  // softmax (global max incl. masked is valid: shift-invariance)
  float mx = -3.0e38f;
#pragma unroll
  for (int tl = 0; tl < 32; ++tl)
#pragma unroll
    for (int g = 0; g < 4; ++g) mx = fmaxf(mx, s[tl][g]);
  mx = fmaxf(mx, __shfl_xor(mx, 16));
  mx = fmaxf(mx, __shfl_xor(mx, 32));
  float sum = 0.f;
#pragma unroll
  for (int tl = 0; tl < 32; ++tl)
#pragma unroll
    for (int g = 0; g < 4; ++g) {
      float e = __expf(s[tl][g] - mx);
      e = ((mw[g] >> tl) & 1u) ? 0.0f : e;
      s[tl][g] = e;
      sum += e;
    }
  sum += __shfl_xor(sum, 16);
  sum += __shfl_xor(sum, 32);
  float inv = (sum > 0.f) ? (1.0f / sum) : 0.0f;   // all-masked row -> 0 output

  // pass 2: O = mfma(P, V^T), unnormalized P (e in [0,1]); normalize at epilogue
  f32x4 o0 = {0.f, 0.f, 0.f, 0.f}, o1 = {0.f, 0.f, 0.f, 0.f};
#pragma unroll
  for (int c = 0; c < 16; ++c) {
    int w0, w1, w2, w3;
    asm("v_cvt_pk_bf16_f32 %0, %1, %2" : "=v"(w0) : "v"(s[2 * c][0]), "v"(s[2 * c][1]));
    asm("v_cvt_pk_bf16_f32 %0, %1, %2" : "=v"(w1) : "v"(s[2 * c][2]), "v"(s[2 * c][3]));
    asm("v_cvt_pk_bf16_f32 %0, %1, %2" : "=v"(w2) : "v"(s[2 * c + 1][0]), "v"(s[2 * c + 1][1]));
    asm("v_cvt_pk_bf16_f32 %0, %1, %2" : "=v"(w3) : "v"(s[2 * c + 1][2]), "v"(s[2 * c + 1][3]));
    *(int2*)&Pb[wave][fr][4 * fs] = make_int2(w0, w1);        // keys 32c + 4fs..+3
    *(int2*)&Pb[wave][fr][16 + 4 * fs] = make_int2(w2, w3);   // keys 32c+16 + 4fs..+3
    asm volatile("s_waitcnt lgkmcnt(0)" ::: "memory");
    bf16x8 af = *(bf16x8*)&Pb[wave][fr][8 * fs];              // P[q=fr][32c + fs*8..+7]
    bf16x8 v0 = *(bf16x8*)&Vt[fr][32 * c + 8 * fs];           // Vt[d=fr][...]
    bf16x8 v1 = *(bf16x8*)&Vt[16 + fr][32 * c + 8 * fs];
    o0 = __builtin_amdgcn_mfma_f32_16x16x32_bf16(af, v0, o0, 0, 0, 0);
    o1 = __builtin_amdgcn_mfma_f32_16x16x32_bf16(af, v1, o1, 0, 0, 0);
  }
  // epilogue: O[q = q0 + fs*4+g][d = fr / 16+fr], normalize by inv of that q-row
#pragma unroll
  for (int g = 0; g < 4; ++g) {
    float iv = __shfl(inv, fs * 4 + g);
    int qq = q0 + fs * 4 + g;
    ob[base + (size_t)qq * 32 + fr] = o0[g] * iv;
    ob[base + (size_t)qq * 32 + 16 + fr] = o1[g] * iv;
  }
}

// ---------------- final: 8*tanh(scores/16), mask, softmax over a, write transposed ----------------
__global__ void final_kernel(const float* __restrict__ scores,
                             const int* __restrict__ asgn, const int* __restrict__ fullm,
                             const int* __restrict__ padm, float* __restrict__ out) {
  int row = blockIdx.x;   // b*512 + t
  int b = row >> 9, t = row & 511;
  int lane = threadIdx.x;
  int qm = asgn[row] | padm[row];
  const float* sp = scores + (size_t)row * 512;
  float v[8];
  int mk[8];
#pragma unroll
  for (int m = 0; m < 8; ++m) {
    int a = lane + (m << 6);
    float val = 8.0f * tanhf(sp[a] * (1.0f / 16.0f));
    int masked = qm | fullm[b * CA + a];
    mk[m] = masked;
    v[m] = masked ? NEGV : val;
  }
  float mx = v[0];
#pragma unroll
  for (int m = 1; m < 8; ++m) mx = fmaxf(mx, v[m]);
#pragma unroll
  for (int off = 32; off >= 1; off >>= 1) mx = fmaxf(mx, __shfl_xor(mx, off));
  float sum = 0.f, e[8];
#pragma unroll
  for (int m = 0; m < 8; ++m) { e[m] = __expf(v[m] - mx); sum += e[m]; }
#pragma unroll
  for (int off = 32; off >= 1; off >>= 1) sum += __shfl_xor(sum, off);
  float inv = 1.0f / sum;
#pragma unroll
  for (int m = 0; m < 8; ++m) {
    int a = lane + (m << 6);
    float p = mk[m] ? 0.0f : e[m] * inv;
    out[(size_t)b * (CA * CT) + (size_t)a * CT + t] = p;   // (B,A,T)
  }
}

extern "C" void kernel_launch(void* const* d_in, const int* in_sizes, int n_in,
                              void* d_out, int out_size, void* d_ws, size_t ws_size,
                              hipStream_t stream) {
  const int* tasks = (const int*)d_in[0];
  const int* agents = (const int*)d_in[1];
  const int* indices = (const int*)d_in[2];
  const float* emb_t = (const float*)d_in[3];
  const float* emb_t_wo = (const float*)d_in[4];
  const float* emb_t_bo = (const float*)d_in[5];
  const float* emb_a = (const float*)d_in[6];
  const float* emb_a_wo = (const float*)d_in[7];
  const float* emb_a_bo = (const float*)d_in[8];
  const float* de_wq = (const float*)d_in[33];
  const float* de_wk = (const float*)d_in[34];
  const float* de_wv = (const float*)d_in[35];
  const float* de_wo = (const float*)d_in[36];
  const float* de_w1 = (const float*)d_in[37];
  const float* de_b1 = (const float*)d_in[38];
  const float* de_w2 = (const float*)d_in[39];
  const float* de_b2 = (const float*)d_in[40];
  const float* de_g1 = (const float*)d_in[41];
  const float* de_be1 = (const float*)d_in[42];
  const float* de_g2 = (const float*)d_in[43];
  const float* de_be2 = (const float*)d_in[44];
  const float* do_wq = (const float*)d_in[45];
  const float* do_wk = (const float*)d_in[46];

  float* ws = (float*)d_ws;
  float* ht = ws + 0;            // 4096x256
  float* ha = ws + 1048576;      // 4096x256
  float* qb = ws + 2097152;      // qb,kb,vb contiguous (for fused QKV)
  float* kb = ws + 3145728;
  float* vb = ws + 4194304;
  float* t1 = ws + 5242880;      // 4096x1024 (FFN mid / attn-out / scores)
  float* t2 = ws + 9437184;      // 4096x256
  int* asgn = (int*)(ws + 10485760);
  int* fullm = asgn + 4096;
  int* padm = asgn + 8192;

  mask_prep_kernel<<<16, 256, 0, stream>>>(tasks, indices, asgn, fullm, padm);
  mask_assign_kernel<<<128, 256, 0, stream>>>(indices, asgn);

  // embeddings
  embed_kernel<<<4096, 64, 0, stream>>>(tasks, emb_t, t2, 4);
  mgemm_kernel<false, true, false><<<dim3(64, 4, 1), 256, 0, stream>>>(
      t2, emb_t_wo, emb_t_bo, ht, 256, 256, 0, 0, 0);
  embed_kernel<<<4096, 64, 0, stream>>>(agents, emb_a, t2, 2);
  mgemm_kernel<false, true, false><<<dim3(64, 4, 1), 256, 0, stream>>>(
      t2, emb_a_wo, emb_a_bo, ha, 256, 256, 0, 0, 0);

  // two encoders, 3 layers each
  for (int enc = 0; enc < 2; ++enc) {
    float* x = enc ? ha : ht;
    int pb = enc ? 21 : 9;
    const float* wq = (const float*)d_in[pb + 0];
    const float* wk = (const float*)d_in[pb + 1];
    const float* wv = (const float*)d_in[pb + 2];
    const float* wo = (const float*)d_in[pb + 3];
    const float* w1 = (const float*)d_in[pb + 4];
    const float* b1 = (const float*)d_in[pb + 5];
    const float* w2 = (const float*)d_in[pb + 6];
    const float* b2 = (const float*)d_in[pb + 7];
    const float* g1 = (const float*)d_in[pb + 8];
    const float* be1 = (const float*)d_in[pb + 9];
    const float* g2 = (const float*)d_in[pb + 10];
    const float* be2 = (const float*)d_in[pb + 11];
    for (int l = 0; l < 3; ++l) {
      mgemm_multi_kernel<<<dim3(64, 4, 3), 256, 0, stream>>>(
          x, wq + l * 65536, wk + l * 65536, wv + l * 65536, qb, 256, 256, 1048576);
      mattn_kernel<0><<<dim3(64, 4, 1), 512, 0, stream>>>(qb, kb, vb, t1, asgn, fullm, padm);
      mgemm_kernel<false, false, false><<<dim3(64, 4, 1), 256, 0, stream>>>(
          t1, wo + l * 65536, nullptr, t2, 256, 256, 0, 0, 0);
      ln_add_kernel<<<4096, 64, 0, stream>>>(x, t2, g1 + l * 256, be1 + l * 256);
      mgemm_kernel<false, true, true><<<dim3(64, 16, 1), 256, 0, stream>>>(
          x, w1 + l * 262144, b1 + l * 1024, t1, 1024, 256, 0, 0, 0);
      mgemm_kernel<false, true, false><<<dim3(64, 4, 1), 256, 0, stream>>>(
          t1, w2 + l * 262144, b2 + l * 256, t2, 256, 1024, 0, 0, 0);
      ln_add_kernel<<<4096, 64, 0, stream>>>(x, t2, g2 + l * 256, be2 + l * 256);
    }
  }

  // decoder cross-attention block (ht := h)
  mgemm_kernel<false, false, false><<<dim3(64, 4, 1), 256, 0, stream>>>(
      ht, de_wq, nullptr, qb, 256, 256, 0, 0, 0);
  mgemm_multi_kernel<<<dim3(64, 4, 2), 256, 0, stream>>>(
      ha, de_wk, de_wv, de_wv, kb, 256, 256, 1048576);
  mattn_kernel<1><<<dim3(64, 4, 1), 512, 0, stream>>>(qb, kb, vb, t1, asgn, fullm, padm);
  mgemm_kernel<false, false, false><<<dim3(64, 4, 1), 256, 0, stream>>>(
      t1, de_wo, nullptr, t2, 256, 256, 0, 0, 0);
  ln_add_kernel<<<4096, 64, 0, stream>>>(ht, t2, de_g1, de_be1);
  mgemm_kernel<false, true, true><<<dim3(64, 8, 1), 256, 0, stream>>>(
      ht, de_w1, de_b1, t1, 512, 256, 0, 0, 0);
  mgemm_kernel<false, true, false><<<dim3(64, 4, 1), 256, 0, stream>>>(
      t1, de_w2, de_b2, t2, 256, 512, 0, 0, 0);
  ln_add_kernel<<<4096, 64, 0, stream>>>(ht, t2, de_g2, de_be2);

  // final scores + softmax + transpose
  mgemm_kernel<false, false, false><<<dim3(64, 4, 1), 256, 0, stream>>>(
      ht, do_wq, nullptr, qb, 256, 256, 0, 0, 0);
  mgemm_kernel<false, false, false><<<dim3(64, 4, 1), 256, 0, stream>>>(
      ha, do_wk, nullptr, kb, 256, 256, 0, 0, 0);
  mgemm_kernel<true, false, false><<<dim3(8, 8, 8), 256, 0, stream>>>(
      qb, kb, nullptr, t1, 512, 256, 131072, 131072, 262144);
  final_kernel<<<4096, 64, 0, stream>>>(t1, asgn, fullm, padm, (float*)d_out);
}

// Round 4
// 703.469 us; speedup vs baseline: 3.6024x; 1.0978x over previous
//
#include <hip/hip_runtime.h>
#include <hip/hip_bf16.h>

// Transformer forward. All-bf16 MFMA GEMMs (pre-transposed bf16 weights,
// bf16 activation shadows) + bf16 MFMA flash attention.
// B=8 T=512 A=512 C=8 D=256 H=8 dh=32 FF=1024 DEC_FF=512 L=3
constexpr int CB = 8;
constexpr int CT = 512;
constexpr int CA = 512;
constexpr int CC = 8;
constexpr int CD = 256;
constexpr float NEGV = -1.0e9f;

typedef __attribute__((ext_vector_type(8))) short bf16x8;
typedef __attribute__((ext_vector_type(4))) float f32x4;

__device__ inline short f2bf(float f) {
  uint32_t u = __float_as_uint(f);
  uint32_t r = (u + 0x7FFFu + ((u >> 16) & 1u)) >> 16;
  return (short)r;
}

// ---------------- masks ----------------
__global__ void mask_prep_kernel(const int* __restrict__ tasks,
                                 const int* __restrict__ indices,
                                 int* __restrict__ asgn, int* __restrict__ fullm,
                                 int* __restrict__ padm) {
  int i = blockIdx.x * blockDim.x + threadIdx.x;
  if (i >= CB * CT) return;
  asgn[i] = 0;
  const int* tp = tasks + i * 4;
  padm[i] = (tp[0] == -1) && (tp[1] == -1) && (tp[2] == -1) && (tp[3] == -1);
  const int* ip = indices + i * CC;
  int full = 1;
#pragma unroll
  for (int c = 0; c < CC; ++c) full &= (ip[c] != -1);
  fullm[i] = full;
}

__global__ void mask_assign_kernel(const int* __restrict__ indices, int* __restrict__ asgn) {
  int i = blockIdx.x * blockDim.x + threadIdx.x;
  if (i >= CB * CA * CC) return;
  int b = i / (CA * CC);
  int idx = indices[i];
  if (idx >= 0) asgn[b * CT + idx] = 1;   // benign race: same value
}

// ---------------- weight pre-transpose: f32 [K][N] -> bf16 [N][K] ----------------
struct TDesc { const float* src; short* dst; int K; int N; int tbase; };
struct TArgs { TDesc d[46]; int nd; };

__global__ __launch_bounds__(256) void trans_kernel(TArgs a) {
  __shared__ short Ts[64][72];
  const int bid = blockIdx.x;
  int w = 0;
#pragma unroll 1
  for (int i = 1; i < a.nd; ++i)
    if (a.d[i].tbase <= bid) w = i;
  const TDesc de = a.d[w];
  const int ti = bid - de.tbase;
  const int ntn = de.N >> 6;
  const int n0 = (ti % ntn) * 64, k0 = (ti / ntn) * 64;
  const int t = threadIdx.x;
  const int kk = t >> 4, c4 = (t & 15) * 4;
#pragma unroll
  for (int r = 0; r < 4; ++r) {
    float4 v = *(const float4*)(de.src + (size_t)(k0 + kk + r * 16) * de.N + n0 + c4);
    Ts[c4 + 0][kk + r * 16] = f2bf(v.x);
    Ts[c4 + 1][kk + r * 16] = f2bf(v.y);
    Ts[c4 + 2][kk + r * 16] = f2bf(v.z);
    Ts[c4 + 3][kk + r * 16] = f2bf(v.w);
  }
  __syncthreads();
  const int n = t >> 3, k8 = (t & 7) * 8;
#pragma unroll
  for (int r = 0; r < 2; ++r)
    *(bf16x8*)(de.dst + (size_t)(n0 + n + r * 32) * de.K + k0 + k8) =
        *(bf16x8*)&Ts[n + r * 32][k8];
}

// ---------------- embedding gather+sum -> bf16 ----------------
__global__ void embed_kernel(const int* __restrict__ toks, const float* __restrict__ table,
                             short* __restrict__ out, int nf) {
  int row = blockIdx.x;
  int lane = threadIdx.x;
  const int* tp = toks + row * nf;
  float4 acc = make_float4(0.f, 0.f, 0.f, 0.f);
  for (int f = 0; f < nf; ++f) {
    int t = 1 + tp[f];
    float4 v = *(const float4*)(table + ((size_t)f * 33 + t) * CD + lane * 4);
    acc.x += v.x; acc.y += v.y; acc.z += v.z; acc.w += v.w;
  }
  short4 o;
  o.x = f2bf(acc.x); o.y = f2bf(acc.y); o.z = f2bf(acc.z); o.w = f2bf(acc.w);
  *(short4*)(out + (size_t)row * CD + lane * 4) = o;
}

// ---------------- residual add + LayerNorm (x f32 in place, + bf16 shadow) ----------------
__global__ void ln_add_kernel(float* __restrict__ x, const float* __restrict__ res,
                              const float* __restrict__ g, const float* __restrict__ b,
                              short* __restrict__ xb) {
  int row = blockIdx.x;
  int lane = threadIdx.x;
  float4 xv = *(const float4*)(x + (size_t)row * CD + lane * 4);
  float4 rv = *(const float4*)(res + (size_t)row * CD + lane * 4);
  float v0 = xv.x + rv.x, v1 = xv.y + rv.y, v2 = xv.z + rv.z, v3 = xv.w + rv.w;
  float s = v0 + v1 + v2 + v3;
  float s2 = v0 * v0 + v1 * v1 + v2 * v2 + v3 * v3;
#pragma unroll
  for (int off = 32; off >= 1; off >>= 1) {
    s += __shfl_xor(s, off);
    s2 += __shfl_xor(s2, off);
  }
  float mean = s * (1.0f / CD);
  float var = s2 * (1.0f / CD) - mean * mean;
  float rstd = rsqrtf(var + 1e-5f);
  float4 gv = *(const float4*)(g + lane * 4);
  float4 bv = *(const float4*)(b + lane * 4);
  float4 o;
  o.x = (v0 - mean) * rstd * gv.x + bv.x;
  o.y = (v1 - mean) * rstd * gv.y + bv.y;
  o.z = (v2 - mean) * rstd * gv.z + bv.z;
  o.w = (v3 - mean) * rstd * gv.w + bv.w;
  *(float4*)(x + (size_t)row * CD + lane * 4) = o;
  short4 ob;
  ob.x = f2bf(o.x); ob.y = f2bf(o.y); ob.z = f2bf(o.z); ob.w = f2bf(o.w);
  *(short4*)(xb + (size_t)row * CD + lane * 4) = ob;
}

// ---------------- bf16 MFMA GEMM body: A bf16 [M][K], B bf16 [N][K] ----------------
// Tile 64x64, BK=64, 256 threads = 4 waves (2x2 layout, 32x32 per wave).
// CMODE: 0 = f32 C, 1 = bf16 C, 2 = both.
template <int CMODE, bool BIAS, bool RELU>
__device__ __forceinline__ void gemm_body(
    const short* __restrict__ Ab, const short* __restrict__ Bb,
    const float* __restrict__ bias, float* __restrict__ Cf, short* __restrict__ Cbf,
    int Ndim, int Kdim, int bm, int bn) {
  __shared__ short As[64][72];
  __shared__ short Bs[64][72];
  const int t = threadIdx.x;
  const int lane = t & 63, wave = t >> 6;
  const int wm = (wave >> 1) * 32, wn = (wave & 1) * 32;
  const int fr = lane & 15, fs = lane >> 4;

  f32x4 acc[2][2] = {};

  for (int k0 = 0; k0 < Kdim; k0 += 64) {
#pragma unroll
    for (int rep = 0; rep < 2; ++rep) {
      int g = rep * 256 + t;
      int row = g >> 3, k8 = (g & 7) * 8;
      *(bf16x8*)&As[row][k8] = *(const bf16x8*)(Ab + (size_t)(bm + row) * Kdim + k0 + k8);
      *(bf16x8*)&Bs[row][k8] = *(const bf16x8*)(Bb + (size_t)(bn + row) * Kdim + k0 + k8);
    }
    __syncthreads();
#pragma unroll
    for (int kk = 0; kk < 2; ++kk) {
      bf16x8 a0 = *(bf16x8*)&As[wm + fr][kk * 32 + fs * 8];
      bf16x8 a1 = *(bf16x8*)&As[wm + 16 + fr][kk * 32 + fs * 8];
      bf16x8 b0 = *(bf16x8*)&Bs[wn + fr][kk * 32 + fs * 8];
      bf16x8 b1 = *(bf16x8*)&Bs[wn + 16 + fr][kk * 32 + fs * 8];
      acc[0][0] = __builtin_amdgcn_mfma_f32_16x16x32_bf16(a0, b0, acc[0][0], 0, 0, 0);
      acc[0][1] = __builtin_amdgcn_mfma_f32_16x16x32_bf16(a0, b1, acc[0][1], 0, 0, 0);
      acc[1][0] = __builtin_amdgcn_mfma_f32_16x16x32_bf16(a1, b0, acc[1][0], 0, 0, 0);
      acc[1][1] = __builtin_amdgcn_mfma_f32_16x16x32_bf16(a1, b1, acc[1][1], 0, 0, 0);
    }
    __syncthreads();
  }

#pragma unroll
  for (int fi = 0; fi < 2; ++fi)
#pragma unroll
    for (int fj = 0; fj < 2; ++fj) {
      int row0 = bm + wm + fi * 16 + fs * 4;
      int col = bn + wn + fj * 16 + fr;
      float bv = BIAS ? bias[col] : 0.0f;
#pragma unroll
      for (int r = 0; r < 4; ++r) {
        float v = acc[fi][fj][r] + bv;
        if (RELU) v = fmaxf(v, 0.0f);
        if (CMODE == 0 || CMODE == 2) Cf[(size_t)(row0 + r) * Ndim + col] = v;
        if (CMODE == 1 || CMODE == 2) Cbf[(size_t)(row0 + r) * Ndim + col] = f2bf(v);
      }
    }
}

template <int CMODE, bool BIAS, bool RELU>
__global__ __launch_bounds__(256) void mgemm_kernel(
    const short* __restrict__ A, const short* __restrict__ Bm,
    const float* __restrict__ bias, float* __restrict__ Cf, short* __restrict__ Cbf,
    int Ndim, int Kdim, long long sA, long long sB, long long sC) {
  gemm_body<CMODE, BIAS, RELU>(A + (size_t)blockIdx.z * sA, Bm + (size_t)blockIdx.z * sB,
                               bias,
                               Cf ? Cf + (size_t)blockIdx.z * sC : nullptr,
                               Cbf ? Cbf + (size_t)blockIdx.z * sC : nullptr,
                               Ndim, Kdim, blockIdx.x * 64, blockIdx.y * 64);
}

// fused multi-GEMM: blockIdx.z selects (A,B) pair; C = Cbase + z*strideC (bf16 out)
__global__ __launch_bounds__(256) void mgemm_multi_kernel(
    const short* __restrict__ A0, const short* __restrict__ B0,
    const short* __restrict__ A1, const short* __restrict__ B1,
    const short* __restrict__ A2, const short* __restrict__ B2,
    short* __restrict__ C, int Ndim, int Kdim, long long strideC) {
  const short* Ab = (blockIdx.z == 0) ? A0 : (blockIdx.z == 1) ? A1 : A2;
  const short* Bb = (blockIdx.z == 0) ? B0 : (blockIdx.z == 1) ? B1 : B2;
  gemm_body<1, false, false>(Ab, Bb, nullptr, nullptr, C + (size_t)blockIdx.z * strideC,
                             Ndim, Kdim, blockIdx.x * 64, blockIdx.y * 64);
}

// ---------------- MFMA flash attention, bf16 I/O ----------------
// q/k/v/o bf16 flat (B*T*D); head (b,h) rows are 32-short chunks at (b*8+h)*16384 + x*32.
// MODE 0: encoder self-attn, key mask padm. MODE 1: decoder, q-mask asgn|padm, key mask fullm.
template <int MODE>
__global__ __launch_bounds__(512) void mattn_kernel(
    const short* __restrict__ qb, const short* __restrict__ kb, const short* __restrict__ vb,
    short* __restrict__ ob,
    const int* __restrict__ asgn, const int* __restrict__ fullm, const int* __restrict__ padm) {
  __shared__ short Ks[512][40];
  __shared__ short Vt[32][520];
  __shared__ short Pb[8][16][40];
  __shared__ unsigned int mwords[16];
  const int bh = blockIdx.x;
  const int b = bh >> 3;
  const size_t base = (size_t)bh * (512 * 32);
  const int tid = threadIdx.x;

  // stage K (direct bf16 copy)
#pragma unroll
  for (int r = 0; r < 4; ++r) {
    int i = r * 512 + tid;
    int row = i >> 2, seg = (i & 3) * 8;
    *(bf16x8*)&Ks[row][seg] = *(const bf16x8*)(kb + base + row * 32 + seg);
  }
  // stage V transposed
  {
    int d = tid & 31, g = tid >> 5;
#pragma unroll
    for (int r = 0; r < 8; ++r) {
      int key0 = (r * 16 + g) * 4;
      const short* vp = vb + base + (size_t)key0 * 32 + d;
      unsigned short p0 = (unsigned short)vp[0];
      unsigned short p1 = (unsigned short)vp[32];
      unsigned short p2 = (unsigned short)vp[64];
      unsigned short p3 = (unsigned short)vp[96];
      int lo = ((int)p0) | (((int)p1) << 16);
      int hi = ((int)p2) | (((int)p3) << 16);
      *(int2*)&Vt[d][key0] = make_int2(lo, hi);
    }
  }
  if (tid < 16) {
    unsigned w = 0;
    for (int tl = 0; tl < 32; ++tl) {
      int key = tl * 16 + tid;
      int m = (MODE == 0) ? padm[b * CT + key] : fullm[b * CA + key];
      w |= ((unsigned)(m != 0)) << tl;
    }
    mwords[tid] = w;
  }
  __syncthreads();

  const int wave = tid >> 6, lane = tid & 63;
  const int fr = lane & 15, fs = lane >> 4;
  const int q0 = blockIdx.y * 128 + wave * 16;
  const int q = q0 + fr;

  bf16x8 qf = *(const bf16x8*)(qb + base + (size_t)q * 32 + fs * 8);

  unsigned qmbits = 0;
  if (MODE == 1) {
    int qm = asgn[b * CT + q] | padm[b * CT + q];
    qmbits = qm ? 0xFFFFFFFFu : 0u;
  }
  unsigned mw[4];
#pragma unroll
  for (int g = 0; g < 4; ++g) mw[g] = mwords[4 * fs + g] | qmbits;

  // pass 1: S^T = mfma(K_tile, Q): lane holds S[key = tl*16 + fs*4+reg][q = fr]
  f32x4 s[32];
#pragma unroll
  for (int tl = 0; tl < 32; ++tl) {
    bf16x8 kf = *(bf16x8*)&Ks[tl * 16 + fr][fs * 8];
    f32x4 z = {0.f, 0.f, 0.f, 0.f};
    s[tl] = __builtin_amdgcn_mfma_f32_16x16x32_bf16(kf, qf, z, 0, 0, 0);
  }
  const float sc = 0.17677669529663687f;   // 1/sqrt(32), folded into exp arg
  float mx = -3.0e38f;
#pragma unroll
  for (int tl = 0; tl < 32; ++tl)
#pragma unroll
    for (int g = 0; g < 4; ++g) mx = fmaxf(mx, s[tl][g]);
  mx = fmaxf(mx, __shfl_xor(mx, 16));
  mx = fmaxf(mx, __shfl_xor(mx, 32));
  float sum = 0.f;
#pragma unroll
  for (int tl = 0; tl < 32; ++tl)
#pragma unroll
    for (int g = 0; g < 4; ++g) {
      float e = __expf((s[tl][g] - mx) * sc);
      e = ((mw[g] >> tl) & 1u) ? 0.0f : e;
      s[tl][g] = e;
      sum += e;
    }
  sum += __shfl_xor(sum, 16);
  sum += __shfl_xor(sum, 32);
  float inv = (sum > 0.f) ? (1.0f / sum) : 0.0f;

  // pass 2: O = mfma(P, V^T), unnormalized P; normalize at epilogue
  f32x4 o0 = {0.f, 0.f, 0.f, 0.f}, o1 = {0.f, 0.f, 0.f, 0.f};
#pragma unroll
  for (int c = 0; c < 16; ++c) {
    int w0, w1, w2, w3;
    asm("v_cvt_pk_bf16_f32 %0, %1, %2" : "=v"(w0) : "v"(s[2 * c][0]), "v"(s[2 * c][1]));
    asm("v_cvt_pk_bf16_f32 %0, %1, %2" : "=v"(w1) : "v"(s[2 * c][2]), "v"(s[2 * c][3]));
    asm("v_cvt_pk_bf16_f32 %0, %1, %2" : "=v"(w2) : "v"(s[2 * c + 1][0]), "v"(s[2 * c + 1][1]));
    asm("v_cvt_pk_bf16_f32 %0, %1, %2" : "=v"(w3) : "v"(s[2 * c + 1][2]), "v"(s[2 * c + 1][3]));
    *(int2*)&Pb[wave][fr][4 * fs] = make_int2(w0, w1);
    *(int2*)&Pb[wave][fr][16 + 4 * fs] = make_int2(w2, w3);
    asm volatile("s_waitcnt lgkmcnt(0)" ::: "memory");
    __builtin_amdgcn_sched_barrier(0);
    bf16x8 af = *(bf16x8*)&Pb[wave][fr][8 * fs];
    bf16x8 v0 = *(bf16x8*)&Vt[fr][32 * c + 8 * fs];
    bf16x8 v1 = *(bf16x8*)&Vt[16 + fr][32 * c + 8 * fs];
    o0 = __builtin_amdgcn_mfma_f32_16x16x32_bf16(af, v0, o0, 0, 0, 0);
    o1 = __builtin_amdgcn_mfma_f32_16x16x32_bf16(af, v1, o1, 0, 0, 0);
  }
#pragma unroll
  for (int g = 0; g < 4; ++g) {
    float iv = __shfl(inv, fs * 4 + g);
    int qq = q0 + fs * 4 + g;
    ob[base + (size_t)qq * 32 + fr] = f2bf(o0[g] * iv);
    ob[base + (size_t)qq * 32 + 16 + fr] = f2bf(o1[g] * iv);
  }
}

// ---------------- final: 8*tanh(scores/16), mask, softmax over a, write transposed ----------------
__global__ void final_kernel(const float* __restrict__ scores,
                             const int* __restrict__ asgn, const int* __restrict__ fullm,
                             const int* __restrict__ padm, float* __restrict__ out) {
  int row = blockIdx.x;   // b*512 + t
  int b = row >> 9, t = row & 511;
  int lane = threadIdx.x;
  int qm = asgn[row] | padm[row];
  const float* sp = scores + (size_t)row * 512;
  float v[8];
  int mk[8];
#pragma unroll
  for (int m = 0; m < 8; ++m) {
    int a = lane + (m << 6);
    float val = 8.0f * tanhf(sp[a] * (1.0f / 16.0f));
    int masked = qm | fullm[b * CA + a];
    mk[m] = masked;
    v[m] = masked ? NEGV : val;
  }
  float mx = v[0];
#pragma unroll
  for (int m = 1; m < 8; ++m) mx = fmaxf(mx, v[m]);
#pragma unroll
  for (int off = 32; off >= 1; off >>= 1) mx = fmaxf(mx, __shfl_xor(mx, off));
  float sum = 0.f, e[8];
#pragma unroll
  for (int m = 0; m < 8; ++m) { e[m] = __expf(v[m] - mx); sum += e[m]; }
#pragma unroll
  for (int off = 32; off >= 1; off >>= 1) sum += __shfl_xor(sum, off);
  float inv = 1.0f / sum;
#pragma unroll
  for (int m = 0; m < 8; ++m) {
    int a = lane + (m << 6);
    float p = mk[m] ? 0.0f : e[m] * inv;
    out[(size_t)b * (CA * CT) + (size_t)a * CT + t] = p;   // (B,A,T)
  }
}

extern "C" void kernel_launch(void* const* d_in, const int* in_sizes, int n_in,
                              void* d_out, int out_size, void* d_ws, size_t ws_size,
                              hipStream_t stream) {
  const int* tasks = (const int*)d_in[0];
  const int* agents = (const int*)d_in[1];
  const int* indices = (const int*)d_in[2];
  const float* emb_t = (const float*)d_in[3];
  const float* emb_t_wo = (const float*)d_in[4];
  const float* emb_t_bo = (const float*)d_in[5];
  const float* emb_a = (const float*)d_in[6];
  const float* emb_a_wo = (const float*)d_in[7];
  const float* emb_a_bo = (const float*)d_in[8];
  const float* de_wq = (const float*)d_in[33];
  const float* de_wk = (const float*)d_in[34];
  const float* de_wv = (const float*)d_in[35];
  const float* de_wo = (const float*)d_in[36];
  const float* de_w1 = (const float*)d_in[37];
  const float* de_b1 = (const float*)d_in[38];
  const float* de_w2 = (const float*)d_in[39];
  const float* de_b2 = (const float*)d_in[40];
  const float* de_g1 = (const float*)d_in[41];
  const float* de_be1 = (const float*)d_in[42];
  const float* de_g2 = (const float*)d_in[43];
  const float* de_be2 = (const float*)d_in[44];
  const float* do_wq = (const float*)d_in[45];
  const float* do_wk = (const float*)d_in[46];

  float* ws = (float*)d_ws;
  float* ht = ws + 0;                            // 4096x256 f32
  float* ha = ws + 1048576;                      // 4096x256 f32
  short* htb = (short*)(ws + 2097152);           // 4096x256 bf16
  short* hab = (short*)(ws + 2621440);
  short* qbs = (short*)(ws + 3145728);           // q/k/v bf16, 1048576 shorts each
  short* kbs = qbs + 1048576;
  short* vbs = qbs + 2097152;
  short* t1b = (short*)(ws + 4718592);           // 4096x1024 bf16 (attn-out / FFN mid)
  float* t2 = ws + 6815744;                      // 4096x256 f32
  float* scores = ws + 7864320;                  // 8x512x512 f32
  short* wT = (short*)(ws + 9961472);            // transposed bf16 weights (~5.5M shorts)
  int* asgn = (int*)(ws + 12800000);
  int* fullm = asgn + 4096;
  int* padm = asgn + 8192;

  // ---- build weight-transpose table ----
  TArgs ta;
  int idx = 0, tb = 0;
  size_t doff = 0;
  short* Wp[46];
  auto addw = [&](const float* s, int K, int N) {
    Wp[idx] = wT + doff;
    ta.d[idx] = {s, wT + doff, K, N, tb};
    tb += (K >> 6) * (N >> 6);
    doff += (size_t)K * N;
    ++idx;
  };
  addw(emb_t_wo, 256, 256);                         // 0
  addw(emb_a_wo, 256, 256);                         // 1
  for (int enc = 0; enc < 2; ++enc) {
    int pb = enc ? 21 : 9;
    const float* wq = (const float*)d_in[pb + 0];
    const float* wk = (const float*)d_in[pb + 1];
    const float* wv = (const float*)d_in[pb + 2];
    const float* wo = (const float*)d_in[pb + 3];
    const float* w1 = (const float*)d_in[pb + 4];
    const float* w2 = (const float*)d_in[pb + 6];
    for (int l = 0; l < 3; ++l) {
      addw(wq + l * 65536, 256, 256);
      addw(wk + l * 65536, 256, 256);
      addw(wv + l * 65536, 256, 256);
      addw(wo + l * 65536, 256, 256);
    }
    for (int l = 0; l < 3; ++l) addw(w1 + l * 262144, 256, 1024);
    for (int l = 0; l < 3; ++l) addw(w2 + l * 262144, 1024, 256);
  }
  addw(de_wq, 256, 256);                            // 38
  addw(de_wk, 256, 256);                            // 39
  addw(de_wv, 256, 256);                            // 40
  addw(de_wo, 256, 256);                            // 41
  addw(de_w1, 256, 512);                            // 42
  addw(de_w2, 512, 256);                            // 43
  addw(do_wq, 256, 256);                            // 44
  addw(do_wk, 256, 256);                            // 45
  ta.nd = idx;

  mask_prep_kernel<<<16, 256, 0, stream>>>(tasks, indices, asgn, fullm, padm);
  mask_assign_kernel<<<128, 256, 0, stream>>>(indices, asgn);
  trans_kernel<<<tb, 256, 0, stream>>>(ta);

  // embeddings (via t1b as bf16 staging)
  embed_kernel<<<4096, 64, 0, stream>>>(tasks, emb_t, t1b, 4);
  mgemm_kernel<2, true, false><<<dim3(64, 4, 1), 256, 0, stream>>>(
      t1b, Wp[0], emb_t_bo, ht, htb, 256, 256, 0, 0, 0);
  embed_kernel<<<4096, 64, 0, stream>>>(agents, emb_a, t1b, 2);
  mgemm_kernel<2, true, false><<<dim3(64, 4, 1), 256, 0, stream>>>(
      t1b, Wp[1], emb_a_bo, ha, hab, 256, 256, 0, 0, 0);

  // two encoders, 3 layers each
  for (int enc = 0; enc < 2; ++enc) {
    float* x = enc ? ha : ht;
    short* xb = enc ? hab : htb;
    int wb = 2 + enc * 18;   // weight-table base for this encoder
    int pb = enc ? 21 : 9;
    const float* b1 = (const float*)d_in[pb + 5];
    const float* b2 = (const float*)d_in[pb + 7];
    const float* g1 = (const float*)d_in[pb + 8];
    const float* be1 = (const float*)d_in[pb + 9];
    const float* g2 = (const float*)d_in[pb + 10];
    const float* be2 = (const float*)d_in[pb + 11];
    for (int l = 0; l < 3; ++l) {
      mgemm_multi_kernel<<<dim3(64, 4, 3), 256, 0, stream>>>(
          xb, Wp[wb + l * 4 + 0], xb, Wp[wb + l * 4 + 1], xb, Wp[wb + l * 4 + 2],
          qbs, 256, 256, 1048576);
      mattn_kernel<0><<<dim3(64, 4, 1), 512, 0, stream>>>(qbs, kbs, vbs, t1b,
                                                          asgn, fullm, padm);
      mgemm_kernel<0, false, false><<<dim3(64, 4, 1), 256, 0, stream>>>(
          t1b, Wp[wb + l * 4 + 3], nullptr, t2, nullptr, 256, 256, 0, 0, 0);
      ln_add_kernel<<<4096, 64, 0, stream>>>(x, t2, g1 + l * 256, be1 + l * 256, xb);
      mgemm_kernel<1, true, true><<<dim3(64, 16, 1), 256, 0, stream>>>(
          xb, Wp[wb + 12 + l], b1 + l * 1024, nullptr, t1b, 1024, 256, 0, 0, 0);
      mgemm_kernel<0, true, false><<<dim3(64, 4, 1), 256, 0, stream>>>(
          t1b, Wp[wb + 15 + l], b2 + l * 256, t2, nullptr, 256, 1024, 0, 0, 0);
      ln_add_kernel<<<4096, 64, 0, stream>>>(x, t2, g2 + l * 256, be2 + l * 256, xb);
    }
  }

  // decoder cross-attention block (ht := h)
  mgemm_multi_kernel<<<dim3(64, 4, 3), 256, 0, stream>>>(
      htb, Wp[38], hab, Wp[39], hab, Wp[40], qbs, 256, 256, 1048576);
  mattn_kernel<1><<<dim3(64, 4, 1), 512, 0, stream>>>(qbs, kbs, vbs, t1b,
                                                      asgn, fullm, padm);
  mgemm_kernel<0, false, false><<<dim3(64, 4, 1), 256, 0, stream>>>(
      t1b, Wp[41], nullptr, t2, nullptr, 256, 256, 0, 0, 0);
  ln_add_kernel<<<4096, 64, 0, stream>>>(ht, t2, de_g1, de_be1, htb);
  mgemm_kernel<1, true, true><<<dim3(64, 8, 1), 256, 0, stream>>>(
      htb, Wp[42], de_b1, nullptr, t1b, 512, 256, 0, 0, 0);
  mgemm_kernel<0, true, false><<<dim3(64, 4, 1), 256, 0, stream>>>(
      t1b, Wp[43], de_b2, t2, nullptr, 256, 512, 0, 0, 0);
  ln_add_kernel<<<4096, 64, 0, stream>>>(ht, t2, de_g2, de_be2, htb);

  // final scores + softmax + transpose
  mgemm_multi_kernel<<<dim3(64, 4, 2), 256, 0, stream>>>(
      htb, Wp[44], hab, Wp[45], htb, Wp[44], qbs, 256, 256, 1048576);
  mgemm_kernel<0, false, false><<<dim3(8, 8, 8), 256, 0, stream>>>(
      qbs, kbs, nullptr, scores, nullptr, 512, 256, 131072, 131072, 262144);
  final_kernel<<<4096, 64, 0, stream>>>(scores, asgn, fullm, padm, (float*)d_out);
}

// Round 6
// 542.648 us; speedup vs baseline: 4.6700x; 1.2964x over previous
//
#include <hip/hip_runtime.h>
#include <hip/hip_bf16.h>

// Transformer forward. All-bf16 MFMA GEMMs (pre-transposed bf16 weights,
// bf16 activation shadows), dual-encoder batched dispatches.
// B=8 T=512 A=512 C=8 D=256 H=8 dh=32 FF=1024 DEC_FF=512 L=3
constexpr int CB = 8;
constexpr int CT = 512;
constexpr int CA = 512;
constexpr int CC = 8;
constexpr int CD = 256;
constexpr float NEGV = -1.0e9f;

typedef __attribute__((ext_vector_type(8))) short bf16x8;
typedef __attribute__((ext_vector_type(4))) float f32x4;

__device__ inline short f2bf(float f) {
  uint32_t u = __float_as_uint(f);
  uint32_t r = (u + 0x7FFFu + ((u >> 16) & 1u)) >> 16;
  return (short)r;
}

// ---------------- masks ----------------
__global__ void mask_prep_kernel(const int* __restrict__ tasks,
                                 const int* __restrict__ indices,
                                 int* __restrict__ asgn, int* __restrict__ fullm,
                                 int* __restrict__ padm) {
  int i = blockIdx.x * blockDim.x + threadIdx.x;
  if (i >= CB * CT) return;
  asgn[i] = 0;
  const int* tp = tasks + i * 4;
  padm[i] = (tp[0] == -1) && (tp[1] == -1) && (tp[2] == -1) && (tp[3] == -1);
  const int* ip = indices + i * CC;
  int full = 1;
#pragma unroll
  for (int c = 0; c < CC; ++c) full &= (ip[c] != -1);
  fullm[i] = full;
}

__global__ void mask_assign_kernel(const int* __restrict__ indices, int* __restrict__ asgn) {
  int i = blockIdx.x * blockDim.x + threadIdx.x;
  if (i >= CB * CA * CC) return;
  int b = i / (CA * CC);
  int idx = indices[i];
  if (idx >= 0) asgn[b * CT + idx] = 1;   // benign race: same value
}

// ---------------- weight pre-transpose: f32 [K][N] -> bf16 [N][K] ----------------
struct TDesc { const float* src; short* dst; int K; int N; int tbase; };
struct TArgs { TDesc d[46]; int nd; };

__global__ __launch_bounds__(256) void trans_kernel(TArgs a) {
  __shared__ short Ts[64][72];
  const int bid = blockIdx.x;
  int w = 0;
#pragma unroll 1
  for (int i = 1; i < a.nd; ++i)
    if (a.d[i].tbase <= bid) w = i;
  const TDesc de = a.d[w];
  const int ti = bid - de.tbase;
  const int ntn = de.N >> 6;
  const int n0 = (ti % ntn) * 64, k0 = (ti / ntn) * 64;
  const int t = threadIdx.x;
  const int kk = t >> 4, c4 = (t & 15) * 4;
#pragma unroll
  for (int r = 0; r < 4; ++r) {
    float4 v = *(const float4*)(de.src + (size_t)(k0 + kk + r * 16) * de.N + n0 + c4);
    Ts[c4 + 0][kk + r * 16] = f2bf(v.x);
    Ts[c4 + 1][kk + r * 16] = f2bf(v.y);
    Ts[c4 + 2][kk + r * 16] = f2bf(v.z);
    Ts[c4 + 3][kk + r * 16] = f2bf(v.w);
  }
  __syncthreads();
  const int n = t >> 3, k8 = (t & 7) * 8;
#pragma unroll
  for (int r = 0; r < 2; ++r)
    *(bf16x8*)(de.dst + (size_t)(n0 + n + r * 32) * de.K + k0 + k8) =
        *(bf16x8*)&Ts[n + r * 32][k8];
}

// ---------------- embedding gather+sum -> bf16 (both tables, one dispatch) ----------------
__global__ void embed2_kernel(const int* __restrict__ tasks, const int* __restrict__ agents,
                              const float* __restrict__ tab_t, const float* __restrict__ tab_a,
                              short* __restrict__ out) {
  int row = blockIdx.x;   // 0..8191
  int lane = threadIdx.x;
  const int* tp;
  const float* table;
  int nf;
  short* dst;
  if (row < 4096) {
    tp = tasks + row * 4; table = tab_t; nf = 4; dst = out + (size_t)row * CD;
  } else {
    int r = row - 4096;
    tp = agents + r * 2; table = tab_a; nf = 2; dst = out + 1048576 + (size_t)r * CD;
  }
  float4 acc = make_float4(0.f, 0.f, 0.f, 0.f);
  for (int f = 0; f < nf; ++f) {
    int t = 1 + tp[f];
    float4 v = *(const float4*)(table + ((size_t)f * 33 + t) * CD + lane * 4);
    acc.x += v.x; acc.y += v.y; acc.z += v.z; acc.w += v.w;
  }
  short4 o;
  o.x = f2bf(acc.x); o.y = f2bf(acc.y); o.z = f2bf(acc.z); o.w = f2bf(acc.w);
  *(short4*)(dst + lane * 4) = o;
}

// ---------------- residual add + LayerNorm, 4 rows/block ----------------
__device__ __forceinline__ void ln_row(float* x, const float* res, const float* g,
                                       const float* b, short* xb, int row, int lane) {
  float4 xv = *(const float4*)(x + (size_t)row * CD + lane * 4);
  float4 rv = *(const float4*)(res + (size_t)row * CD + lane * 4);
  float v0 = xv.x + rv.x, v1 = xv.y + rv.y, v2 = xv.z + rv.z, v3 = xv.w + rv.w;
  float s = v0 + v1 + v2 + v3;
  float s2 = v0 * v0 + v1 * v1 + v2 * v2 + v3 * v3;
#pragma unroll
  for (int off = 32; off >= 1; off >>= 1) {
    s += __shfl_xor(s, off);
    s2 += __shfl_xor(s2, off);
  }
  float mean = s * (1.0f / CD);
  float var = s2 * (1.0f / CD) - mean * mean;
  float rstd = rsqrtf(var + 1e-5f);
  float4 gv = *(const float4*)(g + lane * 4);
  float4 bv = *(const float4*)(b + lane * 4);
  float4 o;
  o.x = (v0 - mean) * rstd * gv.x + bv.x;
  o.y = (v1 - mean) * rstd * gv.y + bv.y;
  o.z = (v2 - mean) * rstd * gv.z + bv.z;
  o.w = (v3 - mean) * rstd * gv.w + bv.w;
  *(float4*)(x + (size_t)row * CD + lane * 4) = o;
  short4 ob;
  ob.x = f2bf(o.x); ob.y = f2bf(o.y); ob.z = f2bf(o.z); ob.w = f2bf(o.w);
  *(short4*)(xb + (size_t)row * CD + lane * 4) = ob;
}

__global__ __launch_bounds__(256) void ln_add1_kernel(
    float* __restrict__ x, const float* __restrict__ res,
    const float* __restrict__ g, const float* __restrict__ b, short* __restrict__ xb) {
  int row = blockIdx.x * 4 + (threadIdx.x >> 6);
  ln_row(x, res, g, b, xb, row, threadIdx.x & 63);
}

__global__ __launch_bounds__(256) void ln_add2_kernel(
    float* __restrict__ x0, const float* __restrict__ r0, const float* __restrict__ g0,
    const float* __restrict__ b0, short* __restrict__ s0,
    float* __restrict__ x1, const float* __restrict__ r1, const float* __restrict__ g1,
    const float* __restrict__ b1, short* __restrict__ s1) {
  int row = blockIdx.x * 4 + (threadIdx.x >> 6);   // 0..8191
  int lane = threadIdx.x & 63;
  if (row < 4096) ln_row(x0, r0, g0, b0, s0, row, lane);
  else ln_row(x1, r1, g1, b1, s1, row - 4096, lane);
}

// ---------------- bf16 MFMA GEMM body: A bf16 [M][K], B bf16 [N][K] ----------------
// Tile 64x64, BK=64, 256 threads = 4 waves (2x2 layout, 32x32 per wave).
// CMODE: 0 = f32 C, 1 = bf16 C, 2 = both.
template <int CMODE, bool BIAS, bool RELU>
__device__ __forceinline__ void gemm_body(
    const short* __restrict__ Ab, const short* __restrict__ Bb,
    const float* __restrict__ bias, float* __restrict__ Cf, short* __restrict__ Cbf,
    int Ndim, int Kdim, int bm, int bn) {
  __shared__ short As[64][72];
  __shared__ short Bs[64][72];
  const int t = threadIdx.x;
  const int lane = t & 63, wave = t >> 6;
  const int wm = (wave >> 1) * 32, wn = (wave & 1) * 32;
  const int fr = lane & 15, fs = lane >> 4;

  f32x4 acc[2][2] = {};

  for (int k0 = 0; k0 < Kdim; k0 += 64) {
#pragma unroll
    for (int rep = 0; rep < 2; ++rep) {
      int g = rep * 256 + t;
      int row = g >> 3, k8 = (g & 7) * 8;
      *(bf16x8*)&As[row][k8] = *(const bf16x8*)(Ab + (size_t)(bm + row) * Kdim + k0 + k8);
      *(bf16x8*)&Bs[row][k8] = *(const bf16x8*)(Bb + (size_t)(bn + row) * Kdim + k0 + k8);
    }
    __syncthreads();
#pragma unroll
    for (int kk = 0; kk < 2; ++kk) {
      bf16x8 a0 = *(bf16x8*)&As[wm + fr][kk * 32 + fs * 8];
      bf16x8 a1 = *(bf16x8*)&As[wm + 16 + fr][kk * 32 + fs * 8];
      bf16x8 b0 = *(bf16x8*)&Bs[wn + fr][kk * 32 + fs * 8];
      bf16x8 b1 = *(bf16x8*)&Bs[wn + 16 + fr][kk * 32 + fs * 8];
      acc[0][0] = __builtin_amdgcn_mfma_f32_16x16x32_bf16(a0, b0, acc[0][0], 0, 0, 0);
      acc[0][1] = __builtin_amdgcn_mfma_f32_16x16x32_bf16(a0, b1, acc[0][1], 0, 0, 0);
      acc[1][0] = __builtin_amdgcn_mfma_f32_16x16x32_bf16(a1, b0, acc[1][0], 0, 0, 0);
      acc[1][1] = __builtin_amdgcn_mfma_f32_16x16x32_bf16(a1, b1, acc[1][1], 0, 0, 0);
    }
    __syncthreads();
  }

#pragma unroll
  for (int fi = 0; fi < 2; ++fi)
#pragma unroll
    for (int fj = 0; fj < 2; ++fj) {
      int row0 = bm + wm + fi * 16 + fs * 4;
      int col = bn + wn + fj * 16 + fr;
      float bv = BIAS ? bias[col] : 0.0f;
#pragma unroll
      for (int r = 0; r < 4; ++r) {
        float v = acc[fi][fj][r] + bv;
        if (RELU) v = fmaxf(v, 0.0f);
        if (CMODE == 0 || CMODE == 2) Cf[(size_t)(row0 + r) * Ndim + col] = v;
        if (CMODE == 1 || CMODE == 2) Cbf[(size_t)(row0 + r) * Ndim + col] = f2bf(v);
      }
    }
}

// generic multi-GEMM: blockIdx.z selects pointer set
struct GArgs {
  const short* A[8];
  const short* Bm[8];
  const float* bias[8];
  float* Cf[8];
  short* Cb[8];
  int Ndim, Kdim;
};

template <int CMODE, bool BIAS, bool RELU>
__global__ __launch_bounds__(256) void mgemm_kernel(GArgs ga) {
  int z = blockIdx.z;
  gemm_body<CMODE, BIAS, RELU>(ga.A[z], ga.Bm[z], ga.bias[z], ga.Cf[z], ga.Cb[z],
                               ga.Ndim, ga.Kdim, blockIdx.x * 64, blockIdx.y * 64);
}

// ---------------- MFMA flash attention, bf16 I/O ----------------
// q/k/v/o bf16 flat; head slot (blockIdx.x) rows are 32-short chunks at bh*16384 + x*32.
// MODE 0: encoder self-attn (bh may cover 2 encoders), key mask padm.
// MODE 1: decoder, q-mask asgn|padm, key mask fullm.
template <int MODE>
__global__ __launch_bounds__(512) void mattn_kernel(
    const short* __restrict__ qb, const short* __restrict__ kb, const short* __restrict__ vb,
    short* __restrict__ ob,
    const int* __restrict__ asgn, const int* __restrict__ fullm, const int* __restrict__ padm) {
  __shared__ short Ks[512][40];
  __shared__ short Vt[32][520];
  __shared__ short Pb[8][16][40];
  __shared__ unsigned int mwords[16];
  const int bh = blockIdx.x;
  const int b = (bh >> 3) & 7;
  const size_t base = (size_t)bh * (512 * 32);
  const int tid = threadIdx.x;

#pragma unroll
  for (int r = 0; r < 4; ++r) {
    int i = r * 512 + tid;
    int row = i >> 2, seg = (i & 3) * 8;
    *(bf16x8*)&Ks[row][seg] = *(const bf16x8*)(kb + base + row * 32 + seg);
  }
  {
    int d = tid & 31, g = tid >> 5;
#pragma unroll
    for (int r = 0; r < 8; ++r) {
      int key0 = (r * 16 + g) * 4;
      const short* vp = vb + base + (size_t)key0 * 32 + d;
      unsigned short p0 = (unsigned short)vp[0];
      unsigned short p1 = (unsigned short)vp[32];
      unsigned short p2 = (unsigned short)vp[64];
      unsigned short p3 = (unsigned short)vp[96];
      int lo = ((int)p0) | (((int)p1) << 16);
      int hi = ((int)p2) | (((int)p3) << 16);
      *(int2*)&Vt[d][key0] = make_int2(lo, hi);
    }
  }
  if (tid < 16) {
    unsigned w = 0;
    for (int tl = 0; tl < 32; ++tl) {
      int key = tl * 16 + tid;
      int m = (MODE == 0) ? padm[b * CT + key] : fullm[b * CA + key];
      w |= ((unsigned)(m != 0)) << tl;
    }
    mwords[tid] = w;
  }
  __syncthreads();

  const int wave = tid >> 6, lane = tid & 63;
  const int fr = lane & 15, fs = lane >> 4;
  const int q0 = blockIdx.y * 128 + wave * 16;
  const int q = q0 + fr;

  bf16x8 qf = *(const bf16x8*)(qb + base + (size_t)q * 32 + fs * 8);

  unsigned qmbits = 0;
  if (MODE == 1) {
    int qm = asgn[b * CT + q] | padm[b * CT + q];
    qmbits = qm ? 0xFFFFFFFFu : 0u;
  }
  unsigned mw[4];
#pragma unroll
  for (int g = 0; g < 4; ++g) mw[g] = mwords[4 * fs + g] | qmbits;

  // pass 1: S^T = mfma(K_tile, Q): lane holds S[key = tl*16 + fs*4+reg][q = fr]
  f32x4 s[32];
#pragma unroll
  for (int tl = 0; tl < 32; ++tl) {
    bf16x8 kf = *(bf16x8*)&Ks[tl * 16 + fr][fs * 8];
    f32x4 z = {0.f, 0.f, 0.f, 0.f};
    s[tl] = __builtin_amdgcn_mfma_f32_16x16x32_bf16(kf, qf, z, 0, 0, 0);
  }
  const float sc = 0.17677669529663687f;   // 1/sqrt(32), folded into exp arg
  float mx = -3.0e38f;
#pragma unroll
  for (int tl = 0; tl < 32; ++tl)
#pragma unroll
    for (int g = 0; g < 4; ++g) mx = fmaxf(mx, s[tl][g]);
  mx = fmaxf(mx, __shfl_xor(mx, 16));
  mx = fmaxf(mx, __shfl_xor(mx, 32));
  float sum = 0.f;
#pragma unroll
  for (int tl = 0; tl < 32; ++tl)
#pragma unroll
    for (int g = 0; g < 4; ++g) {
      float e = __expf((s[tl][g] - mx) * sc);
      e = ((mw[g] >> tl) & 1u) ? 0.0f : e;
      s[tl][g] = e;
      sum += e;
    }
  sum += __shfl_xor(sum, 16);
  sum += __shfl_xor(sum, 32);
  float inv = (sum > 0.f) ? (1.0f / sum) : 0.0f;

  // pass 2: O = mfma(P, V^T), unnormalized P; normalize at epilogue
  f32x4 o0 = {0.f, 0.f, 0.f, 0.f}, o1 = {0.f, 0.f, 0.f, 0.f};
#pragma unroll
  for (int c = 0; c < 16; ++c) {
    int w0, w1, w2, w3;
    asm("v_cvt_pk_bf16_f32 %0, %1, %2" : "=v"(w0) : "v"(s[2 * c][0]), "v"(s[2 * c][1]));
    asm("v_cvt_pk_bf16_f32 %0, %1, %2" : "=v"(w1) : "v"(s[2 * c][2]), "v"(s[2 * c][3]));
    asm("v_cvt_pk_bf16_f32 %0, %1, %2" : "=v"(w2) : "v"(s[2 * c + 1][0]), "v"(s[2 * c + 1][1]));
    asm("v_cvt_pk_bf16_f32 %0, %1, %2" : "=v"(w3) : "v"(s[2 * c + 1][2]), "v"(s[2 * c + 1][3]));
    *(int2*)&Pb[wave][fr][4 * fs] = make_int2(w0, w1);
    *(int2*)&Pb[wave][fr][16 + 4 * fs] = make_int2(w2, w3);
    asm volatile("s_waitcnt lgkmcnt(0)" ::: "memory");
    __builtin_amdgcn_sched_barrier(0);
    bf16x8 af = *(bf16x8*)&Pb[wave][fr][8 * fs];
    bf16x8 v0 = *(bf16x8*)&Vt[fr][32 * c + 8 * fs];
    bf16x8 v1 = *(bf16x8*)&Vt[16 + fr][32 * c + 8 * fs];
    o0 = __builtin_amdgcn_mfma_f32_16x16x32_bf16(af, v0, o0, 0, 0, 0);
    o1 = __builtin_amdgcn_mfma_f32_16x16x32_bf16(af, v1, o1, 0, 0, 0);
  }
#pragma unroll
  for (int g = 0; g < 4; ++g) {
    float iv = __shfl(inv, fs * 4 + g);
    int qq = q0 + fs * 4 + g;
    ob[base + (size_t)qq * 32 + fr] = f2bf(o0[g] * iv);
    ob[base + (size_t)qq * 32 + 16 + fr] = f2bf(o1[g] * iv);
  }
}

// ---------------- final: 8*tanh(scores/16), mask, softmax over a, write transposed ----------------
__global__ void final_kernel(const float* __restrict__ scores,
                             const int* __restrict__ asgn, const int* __restrict__ fullm,
                             const int* __restrict__ padm, float* __restrict__ out) {
  int row = blockIdx.x;   // b*512 + t
  int b = row >> 9, t = row & 511;
  int lane = threadIdx.x;
  int qm = asgn[row] | padm[row];
  const float* sp = scores + (size_t)row * 512;
  float v[8];
  int mk[8];
#pragma unroll
  for (int m = 0; m < 8; ++m) {
    int a = lane + (m << 6);
    float val = 8.0f * tanhf(sp[a] * (1.0f / 16.0f));
    int masked = qm | fullm[b * CA + a];
    mk[m] = masked;
    v[m] = masked ? NEGV : val;
  }
  float mx = v[0];
#pragma unroll
  for (int m = 1; m < 8; ++m) mx = fmaxf(mx, v[m]);
#pragma unroll
  for (int off = 32; off >= 1; off >>= 1) mx = fmaxf(mx, __shfl_xor(mx, off));
  float sum = 0.f, e[8];
#pragma unroll
  for (int m = 0; m < 8; ++m) { e[m] = __expf(v[m] - mx); sum += e[m]; }
#pragma unroll
  for (int off = 32; off >= 1; off >>= 1) sum += __shfl_xor(sum, off);
  float inv = 1.0f / sum;
#pragma unroll
  for (int m = 0; m < 8; ++m) {
    int a = lane + (m << 6);
    float p = mk[m] ? 0.0f : e[m] * inv;
    out[(size_t)b * (CA * CT) + (size_t)a * CT + t] = p;   // (B,A,T)
  }
}

extern "C" void kernel_launch(void* const* d_in, const int* in_sizes, int n_in,
                              void* d_out, int out_size, void* d_ws, size_t ws_size,
                              hipStream_t stream) {
  const int* tasks = (const int*)d_in[0];
  const int* agents = (const int*)d_in[1];
  const int* indices = (const int*)d_in[2];
  const float* emb_t = (const float*)d_in[3];
  const float* emb_t_wo = (const float*)d_in[4];
  const float* emb_t_bo = (const float*)d_in[5];
  const float* emb_a = (const float*)d_in[6];
  const float* emb_a_wo = (const float*)d_in[7];
  const float* emb_a_bo = (const float*)d_in[8];
  const float* de_wq = (const float*)d_in[33];
  const float* de_wk = (const float*)d_in[34];
  const float* de_wv = (const float*)d_in[35];
  const float* de_wo = (const float*)d_in[36];
  const float* de_w1 = (const float*)d_in[37];
  const float* de_b1 = (const float*)d_in[38];
  const float* de_w2 = (const float*)d_in[39];
  const float* de_b2 = (const float*)d_in[40];
  const float* de_g1 = (const float*)d_in[41];
  const float* de_be1 = (const float*)d_in[42];
  const float* de_g2 = (const float*)d_in[43];
  const float* de_be2 = (const float*)d_in[44];
  const float* do_wq = (const float*)d_in[45];
  const float* do_wk = (const float*)d_in[46];

  float* ws = (float*)d_ws;
  float* ht = ws + 0;                      // [0,1M) f32 4096x256
  float* ha = ws + 1048576;                // [1M,2M)
  short* htb = (short*)(ws + 2097152);     // [2M,2.5M) bf16 shadow
  short* hab = (short*)(ws + 2621440);     // [2.5M,3M)
  short* qall = (short*)(ws + 3145728);    // [3M,4M)   2M shorts (both encoders)
  short* kall = (short*)(ws + 4194304);    // [4M,5M)
  short* vall = (short*)(ws + 5242880);    // [5M,6M)
  short* t1b = (short*)(ws + 6291456);     // [6M,10M)  8M shorts (attn-out / FFN mid x2)
  float* scores = ws + 6291456;            // alias t1b (used only after t1b dead)
  float* t2 = ws + 10485760;               // [10M,12M) f32 x2 encoders
  short* wT = (short*)(ws + 12582912);     // [12M,~14.75M) transposed bf16 weights
  int* asgn = (int*)(ws + 15400000);
  int* fullm = asgn + 4096;
  int* padm = asgn + 8192;

  // ---- build weight-transpose table ----
  TArgs ta;
  int idx = 0, tb = 0;
  size_t doff = 0;
  short* Wp[46];
  auto addw = [&](const float* s, int K, int N) {
    Wp[idx] = wT + doff;
    ta.d[idx] = {s, wT + doff, K, N, tb};
    tb += (K >> 6) * (N >> 6);
    doff += (size_t)K * N;
    ++idx;
  };
  addw(emb_t_wo, 256, 256);   // 0
  addw(emb_a_wo, 256, 256);   // 1
  for (int enc = 0; enc < 2; ++enc) {
    int pb = enc ? 21 : 9;
    const float* wq = (const float*)d_in[pb + 0];
    const float* wk = (const float*)d_in[pb + 1];
    const float* wv = (const float*)d_in[pb + 2];
    const float* wo = (const float*)d_in[pb + 3];
    const float* w1 = (const float*)d_in[pb + 4];
    const float* w2 = (const float*)d_in[pb + 6];
    for (int l = 0; l < 3; ++l) {
      addw(wq + l * 65536, 256, 256);
      addw(wk + l * 65536, 256, 256);
      addw(wv + l * 65536, 256, 256);
      addw(wo + l * 65536, 256, 256);
    }
    for (int l = 0; l < 3; ++l) addw(w1 + l * 262144, 256, 1024);
    for (int l = 0; l < 3; ++l) addw(w2 + l * 262144, 1024, 256);
  }
  addw(de_wq, 256, 256);      // 38
  addw(de_wk, 256, 256);      // 39
  addw(de_wv, 256, 256);      // 40
  addw(de_wo, 256, 256);      // 41
  addw(de_w1, 256, 512);      // 42
  addw(de_w2, 512, 256);      // 43
  addw(do_wq, 256, 256);      // 44
  addw(do_wk, 256, 256);      // 45
  ta.nd = idx;

  mask_prep_kernel<<<16, 256, 0, stream>>>(tasks, indices, asgn, fullm, padm);
  mask_assign_kernel<<<128, 256, 0, stream>>>(indices, asgn);
  trans_kernel<<<tb, 256, 0, stream>>>(ta);

  GArgs ga{};

  // embeddings (staged bf16 into t1b halves), then projection+bias into ht/ha (+shadows)
  embed2_kernel<<<8192, 64, 0, stream>>>(tasks, agents, emb_t, emb_a, t1b);
  ga.A[0] = t1b;            ga.Bm[0] = Wp[0]; ga.bias[0] = emb_t_bo; ga.Cf[0] = ht; ga.Cb[0] = htb;
  ga.A[1] = t1b + 1048576;  ga.Bm[1] = Wp[1]; ga.bias[1] = emb_a_bo; ga.Cf[1] = ha; ga.Cb[1] = hab;
  ga.Ndim = 256; ga.Kdim = 256;
  mgemm_kernel<2, true, false><<<dim3(64, 4, 2), 256, 0, stream>>>(ga);

  const float* b1t = (const float*)d_in[14];
  const float* b2t = (const float*)d_in[16];
  const float* g1t = (const float*)d_in[17];
  const float* be1t = (const float*)d_in[18];
  const float* g2t = (const float*)d_in[19];
  const float* be2t = (const float*)d_in[20];
  const float* b1a = (const float*)d_in[26];
  const float* b2a = (const float*)d_in[28];
  const float* g1a = (const float*)d_in[29];
  const float* be1a = (const float*)d_in[30];
  const float* g2a = (const float*)d_in[31];
  const float* be2a = (const float*)d_in[32];

  // both encoders together, 3 layers
  for (int l = 0; l < 3; ++l) {
    // QKV x2 encoders (z=6)
    for (int j = 0; j < 3; ++j) {
      ga.A[j] = htb;     ga.Bm[j] = Wp[2 + l * 4 + j];
      ga.A[3 + j] = hab; ga.Bm[3 + j] = Wp[20 + l * 4 + j];
    }
    short* outs[6] = {qall, kall, vall, qall + 1048576, kall + 1048576, vall + 1048576};
    for (int j = 0; j < 6; ++j) ga.Cb[j] = outs[j];
    ga.Ndim = 256; ga.Kdim = 256;
    mgemm_kernel<1, false, false><<<dim3(64, 4, 6), 256, 0, stream>>>(ga);
    // attention, 128 head-slots (64 enc-t + 64 enc-a)
    mattn_kernel<0><<<dim3(128, 4, 1), 512, 0, stream>>>(qall, kall, vall, t1b,
                                                         asgn, fullm, padm);
    // wo x2
    ga.A[0] = t1b;           ga.Bm[0] = Wp[2 + l * 4 + 3];  ga.Cf[0] = t2;
    ga.A[1] = t1b + 1048576; ga.Bm[1] = Wp[20 + l * 4 + 3]; ga.Cf[1] = t2 + 1048576;
    ga.Ndim = 256; ga.Kdim = 256;
    mgemm_kernel<0, false, false><<<dim3(64, 4, 2), 256, 0, stream>>>(ga);
    ln_add2_kernel<<<2048, 256, 0, stream>>>(ht, t2, g1t + l * 256, be1t + l * 256, htb,
                                             ha, t2 + 1048576, g1a + l * 256, be1a + l * 256, hab);
    // FFN1 x2 (relu+bias, bf16 out)
    ga.A[0] = htb; ga.Bm[0] = Wp[14 + l]; ga.bias[0] = b1t + l * 1024; ga.Cb[0] = t1b;
    ga.A[1] = hab; ga.Bm[1] = Wp[32 + l]; ga.bias[1] = b1a + l * 1024; ga.Cb[1] = t1b + 4194304;
    ga.Ndim = 1024; ga.Kdim = 256;
    mgemm_kernel<1, true, true><<<dim3(64, 16, 2), 256, 0, stream>>>(ga);
    // FFN2 x2 (bias, f32 out)
    ga.A[0] = t1b;           ga.Bm[0] = Wp[17 + l]; ga.bias[0] = b2t + l * 256; ga.Cf[0] = t2;
    ga.A[1] = t1b + 4194304; ga.Bm[1] = Wp[35 + l]; ga.bias[1] = b2a + l * 256; ga.Cf[1] = t2 + 1048576;
    ga.Ndim = 256; ga.Kdim = 1024;
    mgemm_kernel<0, true, false><<<dim3(64, 4, 2), 256, 0, stream>>>(ga);
    ln_add2_kernel<<<2048, 256, 0, stream>>>(ht, t2, g2t + l * 256, be2t + l * 256, htb,
                                             ha, t2 + 1048576, g2a + l * 256, be2a + l * 256, hab);
  }

  // decoder cross-attention block (ht := h)
  ga.A[0] = htb; ga.Bm[0] = Wp[38]; ga.Cb[0] = qall;
  ga.A[1] = hab; ga.Bm[1] = Wp[39]; ga.Cb[1] = kall;
  ga.A[2] = hab; ga.Bm[2] = Wp[40]; ga.Cb[2] = vall;
  ga.Ndim = 256; ga.Kdim = 256;
  mgemm_kernel<1, false, false><<<dim3(64, 4, 3), 256, 0, stream>>>(ga);
  mattn_kernel<1><<<dim3(64, 4, 1), 512, 0, stream>>>(qall, kall, vall, t1b,
                                                      asgn, fullm, padm);
  ga.A[0] = t1b; ga.Bm[0] = Wp[41]; ga.Cf[0] = t2;
  ga.Ndim = 256; ga.Kdim = 256;
  mgemm_kernel<0, false, false><<<dim3(64, 4, 1), 256, 0, stream>>>(ga);
  ln_add1_kernel<<<1024, 256, 0, stream>>>(ht, t2, de_g1, de_be1, htb);
  ga.A[0] = htb; ga.Bm[0] = Wp[42]; ga.bias[0] = de_b1; ga.Cb[0] = t1b;
  ga.Ndim = 512; ga.Kdim = 256;
  mgemm_kernel<1, true, true><<<dim3(64, 8, 1), 256, 0, stream>>>(ga);
  ga.A[0] = t1b; ga.Bm[0] = Wp[43]; ga.bias[0] = de_b2; ga.Cf[0] = t2;
  ga.Ndim = 256; ga.Kdim = 512;
  mgemm_kernel<0, true, false><<<dim3(64, 4, 1), 256, 0, stream>>>(ga);
  ln_add1_kernel<<<1024, 256, 0, stream>>>(ht, t2, de_g2, de_be2, htb);

  // final scores + softmax + transpose
  ga.A[0] = htb; ga.Bm[0] = Wp[44]; ga.Cb[0] = qall;
  ga.A[1] = hab; ga.Bm[1] = Wp[45]; ga.Cb[1] = kall;
  ga.Ndim = 256; ga.Kdim = 256;
  mgemm_kernel<1, false, false><<<dim3(64, 4, 2), 256, 0, stream>>>(ga);
  for (int b = 0; b < 8; ++b) {
    ga.A[b] = qall + (size_t)b * 131072;
    ga.Bm[b] = kall + (size_t)b * 131072;
    ga.Cf[b] = scores + (size_t)b * 262144;
  }
  ga.Ndim = 512; ga.Kdim = 256;
  mgemm_kernel<0, false, false><<<dim3(8, 8, 8), 256, 0, stream>>>(ga);
  final_kernel<<<4096, 64, 0, stream>>>(scores, asgn, fullm, padm, (float*)d_out);
}

// Round 7
// 487.688 us; speedup vs baseline: 5.1962x; 1.1127x over previous
//
#include <hip/hip_runtime.h>
#include <hip/hip_bf16.h>

// Transformer forward. All-bf16 MFMA GEMMs (pre-transposed bf16 weights,
// bf16 activation shadows), 128x64 GEMM tiles, dual-encoder batched dispatches.
// B=8 T=512 A=512 C=8 D=256 H=8 dh=32 FF=1024 DEC_FF=512 L=3
constexpr int CB = 8;
constexpr int CT = 512;
constexpr int CA = 512;
constexpr int CC = 8;
constexpr int CD = 256;
constexpr float NEGV = -1.0e9f;

typedef __attribute__((ext_vector_type(8))) short bf16x8;
typedef __attribute__((ext_vector_type(4))) float f32x4;

__device__ inline short f2bf(float f) {
  uint32_t u = __float_as_uint(f);
  uint32_t r = (u + 0x7FFFu + ((u >> 16) & 1u)) >> 16;
  return (short)r;
}

// ---------------- masks ----------------
__global__ void mask_prep_kernel(const int* __restrict__ tasks,
                                 const int* __restrict__ indices,
                                 int* __restrict__ asgn, int* __restrict__ fullm,
                                 int* __restrict__ padm) {
  int i = blockIdx.x * blockDim.x + threadIdx.x;
  if (i >= CB * CT) return;
  asgn[i] = 0;
  const int* tp = tasks + i * 4;
  padm[i] = (tp[0] == -1) && (tp[1] == -1) && (tp[2] == -1) && (tp[3] == -1);
  const int* ip = indices + i * CC;
  int full = 1;
#pragma unroll
  for (int c = 0; c < CC; ++c) full &= (ip[c] != -1);
  fullm[i] = full;
}

__global__ void mask_assign_kernel(const int* __restrict__ indices, int* __restrict__ asgn) {
  int i = blockIdx.x * blockDim.x + threadIdx.x;
  if (i >= CB * CA * CC) return;
  int b = i / (CA * CC);
  int idx = indices[i];
  if (idx >= 0) asgn[b * CT + idx] = 1;   // benign race: same value
}

// ---------------- weight pre-transpose: f32 [K][N] -> bf16 [N][K] ----------------
struct TDesc { const float* src; short* dst; int K; int N; int tbase; };
struct TArgs { TDesc d[46]; int nd; };

__global__ __launch_bounds__(256) void trans_kernel(TArgs a) {
  __shared__ short Ts[64][72];
  const int bid = blockIdx.x;
  int w = 0;
#pragma unroll 1
  for (int i = 1; i < a.nd; ++i)
    if (a.d[i].tbase <= bid) w = i;
  const TDesc de = a.d[w];
  const int ti = bid - de.tbase;
  const int ntn = de.N >> 6;
  const int n0 = (ti % ntn) * 64, k0 = (ti / ntn) * 64;
  const int t = threadIdx.x;
  const int kk = t >> 4, c4 = (t & 15) * 4;
#pragma unroll
  for (int r = 0; r < 4; ++r) {
    float4 v = *(const float4*)(de.src + (size_t)(k0 + kk + r * 16) * de.N + n0 + c4);
    Ts[c4 + 0][kk + r * 16] = f2bf(v.x);
    Ts[c4 + 1][kk + r * 16] = f2bf(v.y);
    Ts[c4 + 2][kk + r * 16] = f2bf(v.z);
    Ts[c4 + 3][kk + r * 16] = f2bf(v.w);
  }
  __syncthreads();
  const int n = t >> 3, k8 = (t & 7) * 8;
#pragma unroll
  for (int r = 0; r < 2; ++r)
    *(bf16x8*)(de.dst + (size_t)(n0 + n + r * 32) * de.K + k0 + k8) =
        *(bf16x8*)&Ts[n + r * 32][k8];
}

// ---------------- embedding gather+sum -> bf16 (both tables, one dispatch) ----------------
__global__ void embed2_kernel(const int* __restrict__ tasks, const int* __restrict__ agents,
                              const float* __restrict__ tab_t, const float* __restrict__ tab_a,
                              short* __restrict__ out) {
  int row = blockIdx.x;   // 0..8191
  int lane = threadIdx.x;
  const int* tp;
  const float* table;
  int nf;
  short* dst;
  if (row < 4096) {
    tp = tasks + row * 4; table = tab_t; nf = 4; dst = out + (size_t)row * CD;
  } else {
    int r = row - 4096;
    tp = agents + r * 2; table = tab_a; nf = 2; dst = out + 1048576 + (size_t)r * CD;
  }
  float4 acc = make_float4(0.f, 0.f, 0.f, 0.f);
  for (int f = 0; f < nf; ++f) {
    int t = 1 + tp[f];
    float4 v = *(const float4*)(table + ((size_t)f * 33 + t) * CD + lane * 4);
    acc.x += v.x; acc.y += v.y; acc.z += v.z; acc.w += v.w;
  }
  short4 o;
  o.x = f2bf(acc.x); o.y = f2bf(acc.y); o.z = f2bf(acc.z); o.w = f2bf(acc.w);
  *(short4*)(dst + lane * 4) = o;
}

// ---------------- residual add + LayerNorm, 4 rows/block ----------------
__device__ __forceinline__ void ln_row(float* x, const float* res, const float* g,
                                       const float* b, short* xb, int row, int lane) {
  float4 xv = *(const float4*)(x + (size_t)row * CD + lane * 4);
  float4 rv = *(const float4*)(res + (size_t)row * CD + lane * 4);
  float v0 = xv.x + rv.x, v1 = xv.y + rv.y, v2 = xv.z + rv.z, v3 = xv.w + rv.w;
  float s = v0 + v1 + v2 + v3;
  float s2 = v0 * v0 + v1 * v1 + v2 * v2 + v3 * v3;
#pragma unroll
  for (int off = 32; off >= 1; off >>= 1) {
    s += __shfl_xor(s, off);
    s2 += __shfl_xor(s2, off);
  }
  float mean = s * (1.0f / CD);
  float var = s2 * (1.0f / CD) - mean * mean;
  float rstd = rsqrtf(var + 1e-5f);
  float4 gv = *(const float4*)(g + lane * 4);
  float4 bv = *(const float4*)(b + lane * 4);
  float4 o;
  o.x = (v0 - mean) * rstd * gv.x + bv.x;
  o.y = (v1 - mean) * rstd * gv.y + bv.y;
  o.z = (v2 - mean) * rstd * gv.z + bv.z;
  o.w = (v3 - mean) * rstd * gv.w + bv.w;
  *(float4*)(x + (size_t)row * CD + lane * 4) = o;
  short4 ob;
  ob.x = f2bf(o.x); ob.y = f2bf(o.y); ob.z = f2bf(o.z); ob.w = f2bf(o.w);
  *(short4*)(xb + (size_t)row * CD + lane * 4) = ob;
}

__global__ __launch_bounds__(256) void ln_add1_kernel(
    float* __restrict__ x, const float* __restrict__ res,
    const float* __restrict__ g, const float* __restrict__ b, short* __restrict__ xb) {
  int row = blockIdx.x * 4 + (threadIdx.x >> 6);
  ln_row(x, res, g, b, xb, row, threadIdx.x & 63);
}

__global__ __launch_bounds__(256) void ln_add2_kernel(
    float* __restrict__ x0, const float* __restrict__ r0, const float* __restrict__ g0,
    const float* __restrict__ b0, short* __restrict__ s0,
    float* __restrict__ x1, const float* __restrict__ r1, const float* __restrict__ g1,
    const float* __restrict__ b1, short* __restrict__ s1) {
  int row = blockIdx.x * 4 + (threadIdx.x >> 6);   // 0..8191
  int lane = threadIdx.x & 63;
  if (row < 4096) ln_row(x0, r0, g0, b0, s0, row, lane);
  else ln_row(x1, r1, g1, b1, s1, row - 4096, lane);
}

// ---------------- bf16 MFMA GEMM body: A bf16 [M][K], B bf16 [N][K] ----------------
// Tile 128x64, BK=64, 256 threads = 4 waves; wave w owns rows [w*32, w*32+32) x all 64 cols.
// Per K-32 slice per wave: 8 MFMA vs 6 ds_read_b128. CMODE: 0 = f32 C, 1 = bf16 C, 2 = both.
template <int CMODE, bool BIAS, bool RELU>
__device__ __forceinline__ void gemm_body(
    const short* __restrict__ Ab, const short* __restrict__ Bb,
    const float* __restrict__ bias, float* __restrict__ Cf, short* __restrict__ Cbf,
    int Ndim, int Kdim, int bm, int bn) {
  __shared__ short As[128][72];
  __shared__ short Bs[64][72];
  const int t = threadIdx.x;
  const int lane = t & 63, wave = t >> 6;
  const int wm = wave * 32;
  const int fr = lane & 15, fs = lane >> 4;
  const int srow = t >> 3, sk8 = (t & 7) * 8;   // staging: 32 rows per round

  f32x4 acc[2][4] = {};

  for (int k0 = 0; k0 < Kdim; k0 += 64) {
#pragma unroll
    for (int r = 0; r < 4; ++r)
      *(bf16x8*)&As[srow + r * 32][sk8] =
          *(const bf16x8*)(Ab + (size_t)(bm + srow + r * 32) * Kdim + k0 + sk8);
#pragma unroll
    for (int r = 0; r < 2; ++r)
      *(bf16x8*)&Bs[srow + r * 32][sk8] =
          *(const bf16x8*)(Bb + (size_t)(bn + srow + r * 32) * Kdim + k0 + sk8);
    __syncthreads();
#pragma unroll
    for (int kk = 0; kk < 2; ++kk) {
      bf16x8 a0 = *(bf16x8*)&As[wm + fr][kk * 32 + fs * 8];
      bf16x8 a1 = *(bf16x8*)&As[wm + 16 + fr][kk * 32 + fs * 8];
      bf16x8 bf0 = *(bf16x8*)&Bs[fr][kk * 32 + fs * 8];
      bf16x8 bf1 = *(bf16x8*)&Bs[16 + fr][kk * 32 + fs * 8];
      bf16x8 bf2 = *(bf16x8*)&Bs[32 + fr][kk * 32 + fs * 8];
      bf16x8 bf3 = *(bf16x8*)&Bs[48 + fr][kk * 32 + fs * 8];
      acc[0][0] = __builtin_amdgcn_mfma_f32_16x16x32_bf16(a0, bf0, acc[0][0], 0, 0, 0);
      acc[0][1] = __builtin_amdgcn_mfma_f32_16x16x32_bf16(a0, bf1, acc[0][1], 0, 0, 0);
      acc[0][2] = __builtin_amdgcn_mfma_f32_16x16x32_bf16(a0, bf2, acc[0][2], 0, 0, 0);
      acc[0][3] = __builtin_amdgcn_mfma_f32_16x16x32_bf16(a0, bf3, acc[0][3], 0, 0, 0);
      acc[1][0] = __builtin_amdgcn_mfma_f32_16x16x32_bf16(a1, bf0, acc[1][0], 0, 0, 0);
      acc[1][1] = __builtin_amdgcn_mfma_f32_16x16x32_bf16(a1, bf1, acc[1][1], 0, 0, 0);
      acc[1][2] = __builtin_amdgcn_mfma_f32_16x16x32_bf16(a1, bf2, acc[1][2], 0, 0, 0);
      acc[1][3] = __builtin_amdgcn_mfma_f32_16x16x32_bf16(a1, bf3, acc[1][3], 0, 0, 0);
    }
    __syncthreads();
  }

#pragma unroll
  for (int fi = 0; fi < 2; ++fi)
#pragma unroll
    for (int fj = 0; fj < 4; ++fj) {
      int row0 = bm + wm + fi * 16 + fs * 4;
      int col = bn + fj * 16 + fr;
      float bv = BIAS ? bias[col] : 0.0f;
#pragma unroll
      for (int r = 0; r < 4; ++r) {
        float v = acc[fi][fj][r] + bv;
        if (RELU) v = fmaxf(v, 0.0f);
        if (CMODE == 0 || CMODE == 2) Cf[(size_t)(row0 + r) * Ndim + col] = v;
        if (CMODE == 1 || CMODE == 2) Cbf[(size_t)(row0 + r) * Ndim + col] = f2bf(v);
      }
    }
}

// generic multi-GEMM: blockIdx.z selects pointer set
struct GArgs {
  const short* A[8];
  const short* Bm[8];
  const float* bias[8];
  float* Cf[8];
  short* Cb[8];
  int Ndim, Kdim;
};

template <int CMODE, bool BIAS, bool RELU>
__global__ __launch_bounds__(256) void mgemm_kernel(GArgs ga) {
  int z = blockIdx.z;
  gemm_body<CMODE, BIAS, RELU>(ga.A[z], ga.Bm[z], ga.bias[z], ga.Cf[z], ga.Cb[z],
                               ga.Ndim, ga.Kdim, blockIdx.x * 128, blockIdx.y * 64);
}

// ---------------- MFMA flash attention, bf16 I/O ----------------
// q/k/v/o bf16 flat; head slot (blockIdx.x) rows are 32-short chunks at bh*16384 + x*32.
// MODE 0: encoder self-attn (bh may cover 2 encoders), key mask padm.
// MODE 1: decoder, q-mask asgn|padm, key mask fullm.
template <int MODE>
__global__ __launch_bounds__(512) void mattn_kernel(
    const short* __restrict__ qb, const short* __restrict__ kb, const short* __restrict__ vb,
    short* __restrict__ ob,
    const int* __restrict__ asgn, const int* __restrict__ fullm, const int* __restrict__ padm) {
  __shared__ short Ks[512][40];
  __shared__ short Vt[32][520];
  __shared__ short Pb[8][16][40];
  __shared__ unsigned int mwords[16];
  const int bh = blockIdx.x;
  const int b = (bh >> 3) & 7;
  const size_t base = (size_t)bh * (512 * 32);
  const int tid = threadIdx.x;

#pragma unroll
  for (int r = 0; r < 4; ++r) {
    int i = r * 512 + tid;
    int row = i >> 2, seg = (i & 3) * 8;
    *(bf16x8*)&Ks[row][seg] = *(const bf16x8*)(kb + base + row * 32 + seg);
  }
  {
    int d = tid & 31, g = tid >> 5;
#pragma unroll
    for (int r = 0; r < 8; ++r) {
      int key0 = (r * 16 + g) * 4;
      const short* vp = vb + base + (size_t)key0 * 32 + d;
      unsigned short p0 = (unsigned short)vp[0];
      unsigned short p1 = (unsigned short)vp[32];
      unsigned short p2 = (unsigned short)vp[64];
      unsigned short p3 = (unsigned short)vp[96];
      int lo = ((int)p0) | (((int)p1) << 16);
      int hi = ((int)p2) | (((int)p3) << 16);
      *(int2*)&Vt[d][key0] = make_int2(lo, hi);
    }
  }
  if (tid < 16) {
    unsigned w = 0;
    for (int tl = 0; tl < 32; ++tl) {
      int key = tl * 16 + tid;
      int m = (MODE == 0) ? padm[b * CT + key] : fullm[b * CA + key];
      w |= ((unsigned)(m != 0)) << tl;
    }
    mwords[tid] = w;
  }
  __syncthreads();

  const int wave = tid >> 6, lane = tid & 63;
  const int fr = lane & 15, fs = lane >> 4;
  const int q0 = blockIdx.y * 128 + wave * 16;
  const int q = q0 + fr;

  bf16x8 qf = *(const bf16x8*)(qb + base + (size_t)q * 32 + fs * 8);

  unsigned qmbits = 0;
  if (MODE == 1) {
    int qm = asgn[b * CT + q] | padm[b * CT + q];
    qmbits = qm ? 0xFFFFFFFFu : 0u;
  }
  unsigned mw[4];
#pragma unroll
  for (int g = 0; g < 4; ++g) mw[g] = mwords[4 * fs + g] | qmbits;

  // pass 1: S^T = mfma(K_tile, Q): lane holds S[key = tl*16 + fs*4+reg][q = fr]
  f32x4 s[32];
#pragma unroll
  for (int tl = 0; tl < 32; ++tl) {
    bf16x8 kf = *(bf16x8*)&Ks[tl * 16 + fr][fs * 8];
    f32x4 z = {0.f, 0.f, 0.f, 0.f};
    s[tl] = __builtin_amdgcn_mfma_f32_16x16x32_bf16(kf, qf, z, 0, 0, 0);
  }
  const float sc = 0.17677669529663687f;   // 1/sqrt(32), folded into exp arg
  float mx = -3.0e38f;
#pragma unroll
  for (int tl = 0; tl < 32; ++tl)
#pragma unroll
    for (int g = 0; g < 4; ++g) mx = fmaxf(mx, s[tl][g]);
  mx = fmaxf(mx, __shfl_xor(mx, 16));
  mx = fmaxf(mx, __shfl_xor(mx, 32));
  float sum = 0.f;
#pragma unroll
  for (int tl = 0; tl < 32; ++tl)
#pragma unroll
    for (int g = 0; g < 4; ++g) {
      float e = __expf((s[tl][g] - mx) * sc);
      e = ((mw[g] >> tl) & 1u) ? 0.0f : e;
      s[tl][g] = e;
      sum += e;
    }
  sum += __shfl_xor(sum, 16);
  sum += __shfl_xor(sum, 32);
  float inv = (sum > 0.f) ? (1.0f / sum) : 0.0f;

  // pass 2: O = mfma(P, V^T), unnormalized P; normalize at epilogue
  f32x4 o0 = {0.f, 0.f, 0.f, 0.f}, o1 = {0.f, 0.f, 0.f, 0.f};
#pragma unroll
  for (int c = 0; c < 16; ++c) {
    int w0, w1, w2, w3;
    asm("v_cvt_pk_bf16_f32 %0, %1, %2" : "=v"(w0) : "v"(s[2 * c][0]), "v"(s[2 * c][1]));
    asm("v_cvt_pk_bf16_f32 %0, %1, %2" : "=v"(w1) : "v"(s[2 * c][2]), "v"(s[2 * c][3]));
    asm("v_cvt_pk_bf16_f32 %0, %1, %2" : "=v"(w2) : "v"(s[2 * c + 1][0]), "v"(s[2 * c + 1][1]));
    asm("v_cvt_pk_bf16_f32 %0, %1, %2" : "=v"(w3) : "v"(s[2 * c + 1][2]), "v"(s[2 * c + 1][3]));
    *(int2*)&Pb[wave][fr][4 * fs] = make_int2(w0, w1);
    *(int2*)&Pb[wave][fr][16 + 4 * fs] = make_int2(w2, w3);
    asm volatile("s_waitcnt lgkmcnt(0)" ::: "memory");
    __builtin_amdgcn_sched_barrier(0);
    bf16x8 af = *(bf16x8*)&Pb[wave][fr][8 * fs];
    bf16x8 v0 = *(bf16x8*)&Vt[fr][32 * c + 8 * fs];
    bf16x8 v1 = *(bf16x8*)&Vt[16 + fr][32 * c + 8 * fs];
    o0 = __builtin_amdgcn_mfma_f32_16x16x32_bf16(af, v0, o0, 0, 0, 0);
    o1 = __builtin_amdgcn_mfma_f32_16x16x32_bf16(af, v1, o1, 0, 0, 0);
  }
#pragma unroll
  for (int g = 0; g < 4; ++g) {
    float iv = __shfl(inv, fs * 4 + g);
    int qq = q0 + fs * 4 + g;
    ob[base + (size_t)qq * 32 + fr] = f2bf(o0[g] * iv);
    ob[base + (size_t)qq * 32 + 16 + fr] = f2bf(o1[g] * iv);
  }
}

// ---------------- final: 8*tanh(scores/16), mask, softmax over a, write transposed ----------------
__global__ void final_kernel(const float* __restrict__ scores,
                             const int* __restrict__ asgn, const int* __restrict__ fullm,
                             const int* __restrict__ padm, float* __restrict__ out) {
  int row = blockIdx.x;   // b*512 + t
  int b = row >> 9, t = row & 511;
  int lane = threadIdx.x;
  int qm = asgn[row] | padm[row];
  const float* sp = scores + (size_t)row * 512;
  float v[8];
  int mk[8];
#pragma unroll
  for (int m = 0; m < 8; ++m) {
    int a = lane + (m << 6);
    float val = 8.0f * tanhf(sp[a] * (1.0f / 16.0f));
    int masked = qm | fullm[b * CA + a];
    mk[m] = masked;
    v[m] = masked ? NEGV : val;
  }
  float mx = v[0];
#pragma unroll
  for (int m = 1; m < 8; ++m) mx = fmaxf(mx, v[m]);
#pragma unroll
  for (int off = 32; off >= 1; off >>= 1) mx = fmaxf(mx, __shfl_xor(mx, off));
  float sum = 0.f, e[8];
#pragma unroll
  for (int m = 0; m < 8; ++m) { e[m] = __expf(v[m] - mx); sum += e[m]; }
#pragma unroll
  for (int off = 32; off >= 1; off >>= 1) sum += __shfl_xor(sum, off);
  float inv = 1.0f / sum;
#pragma unroll
  for (int m = 0; m < 8; ++m) {
    int a = lane + (m << 6);
    float p = mk[m] ? 0.0f : e[m] * inv;
    out[(size_t)b * (CA * CT) + (size_t)a * CT + t] = p;   // (B,A,T)
  }
}

extern "C" void kernel_launch(void* const* d_in, const int* in_sizes, int n_in,
                              void* d_out, int out_size, void* d_ws, size_t ws_size,
                              hipStream_t stream) {
  const int* tasks = (const int*)d_in[0];
  const int* agents = (const int*)d_in[1];
  const int* indices = (const int*)d_in[2];
  const float* emb_t = (const float*)d_in[3];
  const float* emb_t_wo = (const float*)d_in[4];
  const float* emb_t_bo = (const float*)d_in[5];
  const float* emb_a = (const float*)d_in[6];
  const float* emb_a_wo = (const float*)d_in[7];
  const float* emb_a_bo = (const float*)d_in[8];
  const float* de_wq = (const float*)d_in[33];
  const float* de_wk = (const float*)d_in[34];
  const float* de_wv = (const float*)d_in[35];
  const float* de_wo = (const float*)d_in[36];
  const float* de_w1 = (const float*)d_in[37];
  const float* de_b1 = (const float*)d_in[38];
  const float* de_w2 = (const float*)d_in[39];
  const float* de_b2 = (const float*)d_in[40];
  const float* de_g1 = (const float*)d_in[41];
  const float* de_be1 = (const float*)d_in[42];
  const float* de_g2 = (const float*)d_in[43];
  const float* de_be2 = (const float*)d_in[44];
  const float* do_wq = (const float*)d_in[45];
  const float* do_wk = (const float*)d_in[46];

  float* ws = (float*)d_ws;
  float* ht = ws + 0;                      // [0,1M) f32 4096x256
  float* ha = ws + 1048576;                // [1M,2M)
  short* htb = (short*)(ws + 2097152);     // [2M,2.5M) bf16 shadow
  short* hab = (short*)(ws + 2621440);     // [2.5M,3M)
  short* qall = (short*)(ws + 3145728);    // [3M,4M)   2M shorts (both encoders)
  short* kall = (short*)(ws + 4194304);    // [4M,5M)
  short* vall = (short*)(ws + 5242880);    // [5M,6M)
  short* t1b = (short*)(ws + 6291456);     // [6M,10M)  8M shorts (attn-out / FFN mid x2)
  float* scores = ws + 6291456;            // alias t1b (used only after t1b dead)
  float* t2 = ws + 10485760;               // [10M,12M) f32 x2 encoders
  short* wT = (short*)(ws + 12582912);     // [12M,~14.75M) transposed bf16 weights
  int* asgn = (int*)(ws + 15400000);
  int* fullm = asgn + 4096;
  int* padm = asgn + 8192;

  // ---- build weight-transpose table ----
  TArgs ta;
  int idx = 0, tb = 0;
  size_t doff = 0;
  short* Wp[46];
  auto addw = [&](const float* s, int K, int N) {
    Wp[idx] = wT + doff;
    ta.d[idx] = {s, wT + doff, K, N, tb};
    tb += (K >> 6) * (N >> 6);
    doff += (size_t)K * N;
    ++idx;
  };
  addw(emb_t_wo, 256, 256);   // 0
  addw(emb_a_wo, 256, 256);   // 1
  for (int enc = 0; enc < 2; ++enc) {
    int pb = enc ? 21 : 9;
    const float* wq = (const float*)d_in[pb + 0];
    const float* wk = (const float*)d_in[pb + 1];
    const float* wv = (const float*)d_in[pb + 2];
    const float* wo = (const float*)d_in[pb + 3];
    const float* w1 = (const float*)d_in[pb + 4];
    const float* w2 = (const float*)d_in[pb + 6];
    for (int l = 0; l < 3; ++l) {
      addw(wq + l * 65536, 256, 256);
      addw(wk + l * 65536, 256, 256);
      addw(wv + l * 65536, 256, 256);
      addw(wo + l * 65536, 256, 256);
    }
    for (int l = 0; l < 3; ++l) addw(w1 + l * 262144, 256, 1024);
    for (int l = 0; l < 3; ++l) addw(w2 + l * 262144, 1024, 256);
  }
  addw(de_wq, 256, 256);      // 38
  addw(de_wk, 256, 256);      // 39
  addw(de_wv, 256, 256);      // 40
  addw(de_wo, 256, 256);      // 41
  addw(de_w1, 256, 512);      // 42
  addw(de_w2, 512, 256);      // 43
  addw(do_wq, 256, 256);      // 44
  addw(do_wk, 256, 256);      // 45
  ta.nd = idx;

  mask_prep_kernel<<<16, 256, 0, stream>>>(tasks, indices, asgn, fullm, padm);
  mask_assign_kernel<<<128, 256, 0, stream>>>(indices, asgn);
  trans_kernel<<<tb, 256, 0, stream>>>(ta);

  GArgs ga{};

  // embeddings (staged bf16 into t1b halves), then projection+bias into ht/ha (+shadows)
  embed2_kernel<<<8192, 64, 0, stream>>>(tasks, agents, emb_t, emb_a, t1b);
  ga.A[0] = t1b;            ga.Bm[0] = Wp[0]; ga.bias[0] = emb_t_bo; ga.Cf[0] = ht; ga.Cb[0] = htb;
  ga.A[1] = t1b + 1048576;  ga.Bm[1] = Wp[1]; ga.bias[1] = emb_a_bo; ga.Cf[1] = ha; ga.Cb[1] = hab;
  ga.Ndim = 256; ga.Kdim = 256;
  mgemm_kernel<2, true, false><<<dim3(32, 4, 2), 256, 0, stream>>>(ga);

  const float* b1t = (const float*)d_in[14];
  const float* b2t = (const float*)d_in[16];
  const float* g1t = (const float*)d_in[17];
  const float* be1t = (const float*)d_in[18];
  const float* g2t = (const float*)d_in[19];
  const float* be2t = (const float*)d_in[20];
  const float* b1a = (const float*)d_in[26];
  const float* b2a = (const float*)d_in[28];
  const float* g1a = (const float*)d_in[29];
  const float* be1a = (const float*)d_in[30];
  const float* g2a = (const float*)d_in[31];
  const float* be2a = (const float*)d_in[32];

  // both encoders together, 3 layers
  for (int l = 0; l < 3; ++l) {
    // QKV x2 encoders (z=6)
    for (int j = 0; j < 3; ++j) {
      ga.A[j] = htb;     ga.Bm[j] = Wp[2 + l * 4 + j];
      ga.A[3 + j] = hab; ga.Bm[3 + j] = Wp[20 + l * 4 + j];
    }
    short* outs[6] = {qall, kall, vall, qall + 1048576, kall + 1048576, vall + 1048576};
    for (int j = 0; j < 6; ++j) ga.Cb[j] = outs[j];
    ga.Ndim = 256; ga.Kdim = 256;
    mgemm_kernel<1, false, false><<<dim3(32, 4, 6), 256, 0, stream>>>(ga);
    // attention, 128 head-slots (64 enc-t + 64 enc-a)
    mattn_kernel<0><<<dim3(128, 4, 1), 512, 0, stream>>>(qall, kall, vall, t1b,
                                                         asgn, fullm, padm);
    // wo x2
    ga.A[0] = t1b;           ga.Bm[0] = Wp[2 + l * 4 + 3];  ga.Cf[0] = t2;
    ga.A[1] = t1b + 1048576; ga.Bm[1] = Wp[20 + l * 4 + 3]; ga.Cf[1] = t2 + 1048576;
    ga.Ndim = 256; ga.Kdim = 256;
    mgemm_kernel<0, false, false><<<dim3(32, 4, 2), 256, 0, stream>>>(ga);
    ln_add2_kernel<<<2048, 256, 0, stream>>>(ht, t2, g1t + l * 256, be1t + l * 256, htb,
                                             ha, t2 + 1048576, g1a + l * 256, be1a + l * 256, hab);
    // FFN1 x2 (relu+bias, bf16 out)
    ga.A[0] = htb; ga.Bm[0] = Wp[14 + l]; ga.bias[0] = b1t + l * 1024; ga.Cb[0] = t1b;
    ga.A[1] = hab; ga.Bm[1] = Wp[32 + l]; ga.bias[1] = b1a + l * 1024; ga.Cb[1] = t1b + 4194304;
    ga.Ndim = 1024; ga.Kdim = 256;
    mgemm_kernel<1, true, true><<<dim3(32, 16, 2), 256, 0, stream>>>(ga);
    // FFN2 x2 (bias, f32 out)
    ga.A[0] = t1b;           ga.Bm[0] = Wp[17 + l]; ga.bias[0] = b2t + l * 256; ga.Cf[0] = t2;
    ga.A[1] = t1b + 4194304; ga.Bm[1] = Wp[35 + l]; ga.bias[1] = b2a + l * 256; ga.Cf[1] = t2 + 1048576;
    ga.Ndim = 256; ga.Kdim = 1024;
    mgemm_kernel<0, true, false><<<dim3(32, 4, 2), 256, 0, stream>>>(ga);
    ln_add2_kernel<<<2048, 256, 0, stream>>>(ht, t2, g2t + l * 256, be2t + l * 256, htb,
                                             ha, t2 + 1048576, g2a + l * 256, be2a + l * 256, hab);
  }

  // decoder cross-attention block (ht := h)
  ga.A[0] = htb; ga.Bm[0] = Wp[38]; ga.Cb[0] = qall;
  ga.A[1] = hab; ga.Bm[1] = Wp[39]; ga.Cb[1] = kall;
  ga.A[2] = hab; ga.Bm[2] = Wp[40]; ga.Cb[2] = vall;
  ga.Ndim = 256; ga.Kdim = 256;
  mgemm_kernel<1, false, false><<<dim3(32, 4, 3), 256, 0, stream>>>(ga);
  mattn_kernel<1><<<dim3(64, 4, 1), 512, 0, stream>>>(qall, kall, vall, t1b,
                                                      asgn, fullm, padm);
  ga.A[0] = t1b; ga.Bm[0] = Wp[41]; ga.Cf[0] = t2;
  ga.Ndim = 256; ga.Kdim = 256;
  mgemm_kernel<0, false, false><<<dim3(32, 4, 1), 256, 0, stream>>>(ga);
  ln_add1_kernel<<<1024, 256, 0, stream>>>(ht, t2, de_g1, de_be1, htb);
  ga.A[0] = htb; ga.Bm[0] = Wp[42]; ga.bias[0] = de_b1; ga.Cb[0] = t1b;
  ga.Ndim = 512; ga.Kdim = 256;
  mgemm_kernel<1, true, true><<<dim3(32, 8, 1), 256, 0, stream>>>(ga);
  ga.A[0] = t1b; ga.Bm[0] = Wp[43]; ga.bias[0] = de_b2; ga.Cf[0] = t2;
  ga.Ndim = 256; ga.Kdim = 512;
  mgemm_kernel<0, true, false><<<dim3(32, 4, 1), 256, 0, stream>>>(ga);
  ln_add1_kernel<<<1024, 256, 0, stream>>>(ht, t2, de_g2, de_be2, htb);

  // final scores + softmax + transpose
  ga.A[0] = htb; ga.Bm[0] = Wp[44]; ga.Cb[0] = qall;
  ga.A[1] = hab; ga.Bm[1] = Wp[45]; ga.Cb[1] = kall;
  ga.Ndim = 256; ga.Kdim = 256;
  mgemm_kernel<1, false, false><<<dim3(32, 4, 2), 256, 0, stream>>>(ga);
  for (int b = 0; b < 8; ++b) {
    ga.A[b] = qall + (size_t)b * 131072;
    ga.Bm[b] = kall + (size_t)b * 131072;
    ga.Cf[b] = scores + (size_t)b * 262144;
  }
  ga.Ndim = 512; ga.Kdim = 256;
  mgemm_kernel<0, false, false><<<dim3(4, 8, 8), 256, 0, stream>>>(ga);
  final_kernel<<<4096, 64, 0, stream>>>(scores, asgn, fullm, padm, (float*)d_out);
}

// Round 9
// 483.180 us; speedup vs baseline: 5.2447x; 1.0093x over previous
//
#include <hip/hip_runtime.h>
#include <hip/hip_bf16.h>

// Transformer forward. All-bf16 MFMA GEMMs (pre-transposed bf16 weights,
// bf16 activation shadows), 128x64 GEMM tiles with global_load_lds + XOR-swizzle
// + 2-phase double buffer. Dual-encoder batched dispatches.
// B=8 T=512 A=512 C=8 D=256 H=8 dh=32 FF=1024 DEC_FF=512 L=3
constexpr int CB = 8;
constexpr int CT = 512;
constexpr int CA = 512;
constexpr int CC = 8;
constexpr int CD = 256;
constexpr float NEGV = -1.0e9f;

typedef __attribute__((ext_vector_type(8))) short bf16x8;
typedef __attribute__((ext_vector_type(4))) float f32x4;

__device__ inline short f2bf(float f) {
  uint32_t u = __float_as_uint(f);
  uint32_t r = (u + 0x7FFFu + ((u >> 16) & 1u)) >> 16;
  return (short)r;
}

// ---------------- masks ----------------
__global__ void mask_prep_kernel(const int* __restrict__ tasks,
                                 const int* __restrict__ indices,
                                 int* __restrict__ asgn, int* __restrict__ fullm,
                                 int* __restrict__ padm) {
  int i = blockIdx.x * blockDim.x + threadIdx.x;
  if (i >= CB * CT) return;
  asgn[i] = 0;
  const int* tp = tasks + i * 4;
  padm[i] = (tp[0] == -1) && (tp[1] == -1) && (tp[2] == -1) && (tp[3] == -1);
  const int* ip = indices + i * CC;
  int full = 1;
#pragma unroll
  for (int c = 0; c < CC; ++c) full &= (ip[c] != -1);
  fullm[i] = full;
}

__global__ void mask_assign_kernel(const int* __restrict__ indices, int* __restrict__ asgn) {
  int i = blockIdx.x * blockDim.x + threadIdx.x;
  if (i >= CB * CA * CC) return;
  int b = i / (CA * CC);
  int idx = indices[i];
  if (idx >= 0) asgn[b * CT + idx] = 1;   // benign race: same value
}

// ---------------- weight pre-transpose: f32 [K][N] -> bf16 [N][K] ----------------
struct TDesc { const float* src; short* dst; int K; int N; int tbase; };
struct TArgs { TDesc d[46]; int nd; };

__global__ __launch_bounds__(256) void trans_kernel(TArgs a) {
  __shared__ short Ts[64][72];
  const int bid = blockIdx.x;
  int w = 0;
#pragma unroll 1
  for (int i = 1; i < a.nd; ++i)
    if (a.d[i].tbase <= bid) w = i;
  const TDesc de = a.d[w];
  const int ti = bid - de.tbase;
  const int ntn = de.N >> 6;
  const int n0 = (ti % ntn) * 64, k0 = (ti / ntn) * 64;
  const int t = threadIdx.x;
  const int kk = t >> 4, c4 = (t & 15) * 4;
#pragma unroll
  for (int r = 0; r < 4; ++r) {
    float4 v = *(const float4*)(de.src + (size_t)(k0 + kk + r * 16) * de.N + n0 + c4);
    Ts[c4 + 0][kk + r * 16] = f2bf(v.x);
    Ts[c4 + 1][kk + r * 16] = f2bf(v.y);
    Ts[c4 + 2][kk + r * 16] = f2bf(v.z);
    Ts[c4 + 3][kk + r * 16] = f2bf(v.w);
  }
  __syncthreads();
  const int n = t >> 3, k8 = (t & 7) * 8;
#pragma unroll
  for (int r = 0; r < 2; ++r)
    *(bf16x8*)(de.dst + (size_t)(n0 + n + r * 32) * de.K + k0 + k8) =
        *(bf16x8*)&Ts[n + r * 32][k8];
}

// ---------------- embedding gather+sum -> bf16 (both tables, one dispatch) ----------------
__global__ void embed2_kernel(const int* __restrict__ tasks, const int* __restrict__ agents,
                              const float* __restrict__ tab_t, const float* __restrict__ tab_a,
                              short* __restrict__ out) {
  int row = blockIdx.x;   // 0..8191
  int lane = threadIdx.x;
  const int* tp;
  const float* table;
  int nf;
  short* dst;
  if (row < 4096) {
    tp = tasks + row * 4; table = tab_t; nf = 4; dst = out + (size_t)row * CD;
  } else {
    int r = row - 4096;
    tp = agents + r * 2; table = tab_a; nf = 2; dst = out + 1048576 + (size_t)r * CD;
  }
  float4 acc = make_float4(0.f, 0.f, 0.f, 0.f);
  for (int f = 0; f < nf; ++f) {
    int t = 1 + tp[f];
    float4 v = *(const float4*)(table + ((size_t)f * 33 + t) * CD + lane * 4);
    acc.x += v.x; acc.y += v.y; acc.z += v.z; acc.w += v.w;
  }
  short4 o;
  o.x = f2bf(acc.x); o.y = f2bf(acc.y); o.z = f2bf(acc.z); o.w = f2bf(acc.w);
  *(short4*)(dst + lane * 4) = o;
}

// ---------------- residual add + LayerNorm, 4 rows/block ----------------
__device__ __forceinline__ void ln_row(float* x, const float* res, const float* g,
                                       const float* b, short* xb, int row, int lane) {
  float4 xv = *(const float4*)(x + (size_t)row * CD + lane * 4);
  float4 rv = *(const float4*)(res + (size_t)row * CD + lane * 4);
  float v0 = xv.x + rv.x, v1 = xv.y + rv.y, v2 = xv.z + rv.z, v3 = xv.w + rv.w;
  float s = v0 + v1 + v2 + v3;
  float s2 = v0 * v0 + v1 * v1 + v2 * v2 + v3 * v3;
#pragma unroll
  for (int off = 32; off >= 1; off >>= 1) {
    s += __shfl_xor(s, off);
    s2 += __shfl_xor(s2, off);
  }
  float mean = s * (1.0f / CD);
  float var = s2 * (1.0f / CD) - mean * mean;
  float rstd = rsqrtf(var + 1e-5f);
  float4 gv = *(const float4*)(g + lane * 4);
  float4 bv = *(const float4*)(b + lane * 4);
  float4 o;
  o.x = (v0 - mean) * rstd * gv.x + bv.x;
  o.y = (v1 - mean) * rstd * gv.y + bv.y;
  o.z = (v2 - mean) * rstd * gv.z + bv.z;
  o.w = (v3 - mean) * rstd * gv.w + bv.w;
  *(float4*)(x + (size_t)row * CD + lane * 4) = o;
  short4 ob;
  ob.x = f2bf(o.x); ob.y = f2bf(o.y); ob.z = f2bf(o.z); ob.w = f2bf(o.w);
  *(short4*)(xb + (size_t)row * CD + lane * 4) = ob;
}

__global__ __launch_bounds__(256) void ln_add1_kernel(
    float* __restrict__ x, const float* __restrict__ res,
    const float* __restrict__ g, const float* __restrict__ b, short* __restrict__ xb) {
  int row = blockIdx.x * 4 + (threadIdx.x >> 6);
  ln_row(x, res, g, b, xb, row, threadIdx.x & 63);
}

__global__ __launch_bounds__(256) void ln_add2_kernel(
    float* __restrict__ x0, const float* __restrict__ r0, const float* __restrict__ g0,
    const float* __restrict__ b0, short* __restrict__ s0,
    float* __restrict__ x1, const float* __restrict__ r1, const float* __restrict__ g1,
    const float* __restrict__ b1, short* __restrict__ s1) {
  int row = blockIdx.x * 4 + (threadIdx.x >> 6);   // 0..8191
  int lane = threadIdx.x & 63;
  if (row < 4096) ln_row(x0, r0, g0, b0, s0, row, lane);
  else ln_row(x1, r1, g1, b1, s1, row - 4096, lane);
}

// ---------------- bf16 MFMA GEMM body: A bf16 [M][K], B bf16 [N][K] ----------------
// Tile 128x64, BK=64, 256 threads = 4 waves; wave w owns rows [w*32, w*32+32) x 64 cols.
// LDS linear (row stride 128B) + XOR swizzle: logical chunk c of row r stored at
// physical chunk c^(r&7). Staged via global_load_lds (16B), pre-swizzled global src.
// 2-phase double buffer: stage(next) issued before compute(cur), one barrier per step.
// CMODE: 0 = f32 C, 1 = bf16 C, 2 = both.
template <int CMODE, bool BIAS, bool RELU>
__device__ __forceinline__ void gemm_body(
    const short* __restrict__ Ab, const short* __restrict__ Bb,
    const float* __restrict__ bias, float* __restrict__ Cf, short* __restrict__ Cbf,
    int Ndim, int Kdim, int bm, int bn) {
  __shared__ __align__(16) short As[2][128 * 64];
  __shared__ __align__(16) short Bs[2][64 * 64];
  const int t = threadIdx.x;
  const int lane = t & 63, wave = t >> 6;
  const int wm = wave * 32;
  const int fr = lane & 15, fs = lane >> 4;
  const int fr7 = fr & 7;

  // staging geometry: thread t covers physical chunk (t&7) of row (t>>3) per 32-row round
  const int srow = t >> 3;                      // 0..31
  const int lc = (t & 7) ^ (srow & 7);          // logical chunk fetched by this thread
  const short* Asrc = Ab + (size_t)(bm + srow) * Kdim + lc * 8;
  const short* Bsrc = Bb + (size_t)(bn + srow) * Kdim + lc * 8;

  f32x4 acc[2][4] = {};

  auto stage = [&](int buf, int k0) {
#pragma unroll
    for (int r = 0; r < 4; ++r)
      __builtin_amdgcn_global_load_lds(
          (const __attribute__((address_space(1))) void*)(Asrc + (size_t)(r * 32) * Kdim + k0),
          (__attribute__((address_space(3))) void*)(&As[buf][r * 2048 + wave * 512]),
          16, 0, 0);
#pragma unroll
    for (int r = 0; r < 2; ++r)
      __builtin_amdgcn_global_load_lds(
          (const __attribute__((address_space(1))) void*)(Bsrc + (size_t)(r * 32) * Kdim + k0),
          (__attribute__((address_space(3))) void*)(&Bs[buf][r * 2048 + wave * 512]),
          16, 0, 0);
  };

  stage(0, 0);
  __syncthreads();
  int buf = 0;
#pragma unroll 1
  for (int k0 = 0; k0 < Kdim; k0 += 64) {
    if (k0 + 64 < Kdim) stage(buf ^ 1, k0 + 64);
    const short* A0 = &As[buf][(wm + fr) * 64];
    const short* A1 = &As[buf][(wm + 16 + fr) * 64];
    const short* B0 = &Bs[buf][fr * 64];
    const short* B1 = &Bs[buf][(16 + fr) * 64];
    const short* B2 = &Bs[buf][(32 + fr) * 64];
    const short* B3 = &Bs[buf][(48 + fr) * 64];
#pragma unroll
    for (int kk = 0; kk < 2; ++kk) {
      const int co = (((kk * 4) + fs) ^ fr7) * 8;   // swizzled chunk offset (shorts)
      bf16x8 a0 = *(bf16x8*)(A0 + co);
      bf16x8 a1 = *(bf16x8*)(A1 + co);
      bf16x8 bf0 = *(bf16x8*)(B0 + co);
      bf16x8 bf1 = *(bf16x8*)(B1 + co);
      bf16x8 bf2 = *(bf16x8*)(B2 + co);
      bf16x8 bf3 = *(bf16x8*)(B3 + co);
      acc[0][0] = __builtin_amdgcn_mfma_f32_16x16x32_bf16(a0, bf0, acc[0][0], 0, 0, 0);
      acc[0][1] = __builtin_amdgcn_mfma_f32_16x16x32_bf16(a0, bf1, acc[0][1], 0, 0, 0);
      acc[0][2] = __builtin_amdgcn_mfma_f32_16x16x32_bf16(a0, bf2, acc[0][2], 0, 0, 0);
      acc[0][3] = __builtin_amdgcn_mfma_f32_16x16x32_bf16(a0, bf3, acc[0][3], 0, 0, 0);
      acc[1][0] = __builtin_amdgcn_mfma_f32_16x16x32_bf16(a1, bf0, acc[1][0], 0, 0, 0);
      acc[1][1] = __builtin_amdgcn_mfma_f32_16x16x32_bf16(a1, bf1, acc[1][1], 0, 0, 0);
      acc[1][2] = __builtin_amdgcn_mfma_f32_16x16x32_bf16(a1, bf2, acc[1][2], 0, 0, 0);
      acc[1][3] = __builtin_amdgcn_mfma_f32_16x16x32_bf16(a1, bf3, acc[1][3], 0, 0, 0);
    }
    __syncthreads();   // drains gload_lds (vm) + ds_reads (lgkm) for all waves
    buf ^= 1;
  }

#pragma unroll
  for (int fi = 0; fi < 2; ++fi)
#pragma unroll
    for (int fj = 0; fj < 4; ++fj) {
      int row0 = bm + wm + fi * 16 + fs * 4;
      int col = bn + fj * 16 + fr;
      float bv = BIAS ? bias[col] : 0.0f;
#pragma unroll
      for (int r = 0; r < 4; ++r) {
        float v = acc[fi][fj][r] + bv;
        if (RELU) v = fmaxf(v, 0.0f);
        if (CMODE == 0 || CMODE == 2) Cf[(size_t)(row0 + r) * Ndim + col] = v;
        if (CMODE == 1 || CMODE == 2) Cbf[(size_t)(row0 + r) * Ndim + col] = f2bf(v);
      }
    }
}

// generic multi-GEMM: blockIdx.z selects pointer set
struct GArgs {
  const short* A[8];
  const short* Bm[8];
  const float* bias[8];
  float* Cf[8];
  short* Cb[8];
  int Ndim, Kdim;
};

template <int CMODE, bool BIAS, bool RELU>
__global__ __launch_bounds__(256) void mgemm_kernel(GArgs ga) {
  int z = blockIdx.z;
  gemm_body<CMODE, BIAS, RELU>(ga.A[z], ga.Bm[z], ga.bias[z], ga.Cf[z], ga.Cb[z],
                               ga.Ndim, ga.Kdim, blockIdx.x * 128, blockIdx.y * 64);
}

// ---------------- MFMA flash attention, bf16 I/O ----------------
// q/k/v/o bf16 flat; head slot (blockIdx.x) rows are 32-short chunks at bh*16384 + x*32.
// MODE 0: encoder self-attn (bh may cover 2 encoders), key mask padm.
// MODE 1: decoder, q-mask asgn|padm, key mask fullm.
template <int MODE>
__global__ __launch_bounds__(512) void mattn_kernel(
    const short* __restrict__ qb, const short* __restrict__ kb, const short* __restrict__ vb,
    short* __restrict__ ob,
    const int* __restrict__ asgn, const int* __restrict__ fullm, const int* __restrict__ padm) {
  __shared__ short Ks[512][40];
  __shared__ short Vt[32][520];
  __shared__ short Pb[8][16][40];
  __shared__ unsigned int mwords[16];
  const int bh = blockIdx.x;
  const int b = (bh >> 3) & 7;
  const size_t base = (size_t)bh * (512 * 32);
  const int tid = threadIdx.x;

#pragma unroll
  for (int r = 0; r < 4; ++r) {
    int i = r * 512 + tid;
    int row = i >> 2, seg = (i & 3) * 8;
    *(bf16x8*)&Ks[row][seg] = *(const bf16x8*)(kb + base + row * 32 + seg);
  }
  {
    int d = tid & 31, g = tid >> 5;
#pragma unroll
    for (int r = 0; r < 8; ++r) {
      int key0 = (r * 16 + g) * 4;
      const short* vp = vb + base + (size_t)key0 * 32 + d;
      unsigned short p0 = (unsigned short)vp[0];
      unsigned short p1 = (unsigned short)vp[32];
      unsigned short p2 = (unsigned short)vp[64];
      unsigned short p3 = (unsigned short)vp[96];
      int lo = ((int)p0) | (((int)p1) << 16);
      int hi = ((int)p2) | (((int)p3) << 16);
      *(int2*)&Vt[d][key0] = make_int2(lo, hi);
    }
  }
  if (tid < 16) {
    unsigned w = 0;
    for (int tl = 0; tl < 32; ++tl) {
      int key = tl * 16 + tid;
      int m = (MODE == 0) ? padm[b * CT + key] : fullm[b * CA + key];
      w |= ((unsigned)(m != 0)) << tl;
    }
    mwords[tid] = w;
  }
  __syncthreads();

  const int wave = tid >> 6, lane = tid & 63;
  const int fr = lane & 15, fs = lane >> 4;
  const int q0 = blockIdx.y * 128 + wave * 16;
  const int q = q0 + fr;

  bf16x8 qf = *(const bf16x8*)(qb + base + (size_t)q * 32 + fs * 8);

  unsigned qmbits = 0;
  if (MODE == 1) {
    int qm = asgn[b * CT + q] | padm[b * CT + q];
    qmbits = qm ? 0xFFFFFFFFu : 0u;
  }
  unsigned mw[4];
#pragma unroll
  for (int g = 0; g < 4; ++g) mw[g] = mwords[4 * fs + g] | qmbits;

  // pass 1: S^T = mfma(K_tile, Q): lane holds S[key = tl*16 + fs*4+reg][q = fr]
  f32x4 s[32];
#pragma unroll
  for (int tl = 0; tl < 32; ++tl) {
    bf16x8 kf = *(bf16x8*)&Ks[tl * 16 + fr][fs * 8];
    f32x4 z = {0.f, 0.f, 0.f, 0.f};
    s[tl] = __builtin_amdgcn_mfma_f32_16x16x32_bf16(kf, qf, z, 0, 0, 0);
  }
  const float sc = 0.17677669529663687f;   // 1/sqrt(32), folded into exp arg
  float mx = -3.0e38f;
#pragma unroll
  for (int tl = 0; tl < 32; ++tl)
#pragma unroll
    for (int g = 0; g < 4; ++g) mx = fmaxf(mx, s[tl][g]);
  mx = fmaxf(mx, __shfl_xor(mx, 16));
  mx = fmaxf(mx, __shfl_xor(mx, 32));
  float sum = 0.f;
#pragma unroll
  for (int tl = 0; tl < 32; ++tl)
#pragma unroll
    for (int g = 0; g < 4; ++g) {
      float e = __expf((s[tl][g] - mx) * sc);
      e = ((mw[g] >> tl) & 1u) ? 0.0f : e;
      s[tl][g] = e;
      sum += e;
    }
  sum += __shfl_xor(sum, 16);
  sum += __shfl_xor(sum, 32);
  float inv = (sum > 0.f) ? (1.0f / sum) : 0.0f;

  // pass 2: O = mfma(P, V^T), unnormalized P; normalize at epilogue
  f32x4 o0 = {0.f, 0.f, 0.f, 0.f}, o1 = {0.f, 0.f, 0.f, 0.f};
#pragma unroll
  for (int c = 0; c < 16; ++c) {
    int w0, w1, w2, w3;
    asm("v_cvt_pk_bf16_f32 %0, %1, %2" : "=v"(w0) : "v"(s[2 * c][0]), "v"(s[2 * c][1]));
    asm("v_cvt_pk_bf16_f32 %0, %1, %2" : "=v"(w1) : "v"(s[2 * c][2]), "v"(s[2 * c][3]));
    asm("v_cvt_pk_bf16_f32 %0, %1, %2" : "=v"(w2) : "v"(s[2 * c + 1][0]), "v"(s[2 * c + 1][1]));
    asm("v_cvt_pk_bf16_f32 %0, %1, %2" : "=v"(w3) : "v"(s[2 * c + 1][2]), "v"(s[2 * c + 1][3]));
    *(int2*)&Pb[wave][fr][4 * fs] = make_int2(w0, w1);
    *(int2*)&Pb[wave][fr][16 + 4 * fs] = make_int2(w2, w3);
    asm volatile("s_waitcnt lgkmcnt(0)" ::: "memory");
    __builtin_amdgcn_sched_barrier(0);
    bf16x8 af = *(bf16x8*)&Pb[wave][fr][8 * fs];
    bf16x8 v0 = *(bf16x8*)&Vt[fr][32 * c + 8 * fs];
    bf16x8 v1 = *(bf16x8*)&Vt[16 + fr][32 * c + 8 * fs];
    o0 = __builtin_amdgcn_mfma_f32_16x16x32_bf16(af, v0, o0, 0, 0, 0);
    o1 = __builtin_amdgcn_mfma_f32_16x16x32_bf16(af, v1, o1, 0, 0, 0);
  }
#pragma unroll
  for (int g = 0; g < 4; ++g) {
    float iv = __shfl(inv, fs * 4 + g);
    int qq = q0 + fs * 4 + g;
    ob[base + (size_t)qq * 32 + fr] = f2bf(o0[g] * iv);
    ob[base + (size_t)qq * 32 + 16 + fr] = f2bf(o1[g] * iv);
  }
}

// ---------------- final: 8*tanh(scores/16), mask, softmax over a, write transposed ----------------
__global__ void final_kernel(const float* __restrict__ scores,
                             const int* __restrict__ asgn, const int* __restrict__ fullm,
                             const int* __restrict__ padm, float* __restrict__ out) {
  int row = blockIdx.x;   // b*512 + t
  int b = row >> 9, t = row & 511;
  int lane = threadIdx.x;
  int qm = asgn[row] | padm[row];
  const float* sp = scores + (size_t)row * 512;
  float v[8];
  int mk[8];
#pragma unroll
  for (int m = 0; m < 8; ++m) {
    int a = lane + (m << 6);
    float val = 8.0f * tanhf(sp[a] * (1.0f / 16.0f));
    int masked = qm | fullm[b * CA + a];
    mk[m] = masked;
    v[m] = masked ? NEGV : val;
  }
  float mx = v[0];
#pragma unroll
  for (int m = 1; m < 8; ++m) mx = fmaxf(mx, v[m]);
#pragma unroll
  for (int off = 32; off >= 1; off >>= 1) mx = fmaxf(mx, __shfl_xor(mx, off));
  float sum = 0.f, e[8];
#pragma unroll
  for (int m = 0; m < 8; ++m) { e[m] = __expf(v[m] - mx); sum += e[m]; }
#pragma unroll
  for (int off = 32; off >= 1; off >>= 1) sum += __shfl_xor(sum, off);
  float inv = 1.0f / sum;
#pragma unroll
  for (int m = 0; m < 8; ++m) {
    int a = lane + (m << 6);
    float p = mk[m] ? 0.0f : e[m] * inv;
    out[(size_t)b * (CA * CT) + (size_t)a * CT + t] = p;   // (B,A,T)
  }
}

extern "C" void kernel_launch(void* const* d_in, const int* in_sizes, int n_in,
                              void* d_out, int out_size, void* d_ws, size_t ws_size,
                              hipStream_t stream) {
  const int* tasks = (const int*)d_in[0];
  const int* agents = (const int*)d_in[1];
  const int* indices = (const int*)d_in[2];
  const float* emb_t = (const float*)d_in[3];
  const float* emb_t_wo = (const float*)d_in[4];
  const float* emb_t_bo = (const float*)d_in[5];
  const float* emb_a = (const float*)d_in[6];
  const float* emb_a_wo = (const float*)d_in[7];
  const float* emb_a_bo = (const float*)d_in[8];
  const float* de_wq = (const float*)d_in[33];
  const float* de_wk = (const float*)d_in[34];
  const float* de_wv = (const float*)d_in[35];
  const float* de_wo = (const float*)d_in[36];
  const float* de_w1 = (const float*)d_in[37];
  const float* de_b1 = (const float*)d_in[38];
  const float* de_w2 = (const float*)d_in[39];
  const float* de_b2 = (const float*)d_in[40];
  const float* de_g1 = (const float*)d_in[41];
  const float* de_be1 = (const float*)d_in[42];
  const float* de_g2 = (const float*)d_in[43];
  const float* de_be2 = (const float*)d_in[44];
  const float* do_wq = (const float*)d_in[45];
  const float* do_wk = (const float*)d_in[46];

  float* ws = (float*)d_ws;
  float* ht = ws + 0;                      // [0,1M) f32 4096x256
  float* ha = ws + 1048576;                // [1M,2M)
  short* htb = (short*)(ws + 2097152);     // [2M,2.5M) bf16 shadow
  short* hab = (short*)(ws + 2621440);     // [2.5M,3M)
  short* qall = (short*)(ws + 3145728);    // [3M,4M)   2M shorts (both encoders)
  short* kall = (short*)(ws + 4194304);    // [4M,5M)
  short* vall = (short*)(ws + 5242880);    // [5M,6M)
  short* t1b = (short*)(ws + 6291456);     // [6M,10M)  8M shorts (attn-out / FFN mid x2)
  float* scores = ws + 6291456;            // alias t1b (used only after t1b dead)
  float* t2 = ws + 10485760;               // [10M,12M) f32 x2 encoders
  short* wT = (short*)(ws + 12582912);     // [12M,~14.75M) transposed bf16 weights
  int* asgn = (int*)(ws + 15400000);
  int* fullm = asgn + 4096;
  int* padm = asgn + 8192;

  // ---- build weight-transpose table ----
  TArgs ta;
  int idx = 0, tb = 0;
  size_t doff = 0;
  short* Wp[46];
  auto addw = [&](const float* s, int K, int N) {
    Wp[idx] = wT + doff;
    ta.d[idx] = {s, wT + doff, K, N, tb};
    tb += (K >> 6) * (N >> 6);
    doff += (size_t)K * N;
    ++idx;
  };
  addw(emb_t_wo, 256, 256);   // 0
  addw(emb_a_wo, 256, 256);   // 1
  for (int enc = 0; enc < 2; ++enc) {
    int pb = enc ? 21 : 9;
    const float* wq = (const float*)d_in[pb + 0];
    const float* wk = (const float*)d_in[pb + 1];
    const float* wv = (const float*)d_in[pb + 2];
    const float* wo = (const float*)d_in[pb + 3];
    const float* w1 = (const float*)d_in[pb + 4];
    const float* w2 = (const float*)d_in[pb + 6];
    for (int l = 0; l < 3; ++l) {
      addw(wq + l * 65536, 256, 256);
      addw(wk + l * 65536, 256, 256);
      addw(wv + l * 65536, 256, 256);
      addw(wo + l * 65536, 256, 256);
    }
    for (int l = 0; l < 3; ++l) addw(w1 + l * 262144, 256, 1024);
    for (int l = 0; l < 3; ++l) addw(w2 + l * 262144, 1024, 256);
  }
  addw(de_wq, 256, 256);      // 38
  addw(de_wk, 256, 256);      // 39
  addw(de_wv, 256, 256);      // 40
  addw(de_wo, 256, 256);      // 41
  addw(de_w1, 256, 512);      // 42
  addw(de_w2, 512, 256);      // 43
  addw(do_wq, 256, 256);      // 44
  addw(do_wk, 256, 256);      // 45
  ta.nd = idx;

  mask_prep_kernel<<<16, 256, 0, stream>>>(tasks, indices, asgn, fullm, padm);
  mask_assign_kernel<<<128, 256, 0, stream>>>(indices, asgn);
  trans_kernel<<<tb, 256, 0, stream>>>(ta);

  GArgs ga{};

  // embeddings (staged bf16 into t1b halves), then projection+bias into ht/ha (+shadows)
  embed2_kernel<<<8192, 64, 0, stream>>>(tasks, agents, emb_t, emb_a, t1b);
  ga.A[0] = t1b;            ga.Bm[0] = Wp[0]; ga.bias[0] = emb_t_bo; ga.Cf[0] = ht; ga.Cb[0] = htb;
  ga.A[1] = t1b + 1048576;  ga.Bm[1] = Wp[1]; ga.bias[1] = emb_a_bo; ga.Cf[1] = ha; ga.Cb[1] = hab;
  ga.Ndim = 256; ga.Kdim = 256;
  mgemm_kernel<2, true, false><<<dim3(32, 4, 2), 256, 0, stream>>>(ga);

  const float* b1t = (const float*)d_in[14];
  const float* b2t = (const float*)d_in[16];
  const float* g1t = (const float*)d_in[17];
  const float* be1t = (const float*)d_in[18];
  const float* g2t = (const float*)d_in[19];
  const float* be2t = (const float*)d_in[20];
  const float* b1a = (const float*)d_in[26];
  const float* b2a = (const float*)d_in[28];
  const float* g1a = (const float*)d_in[29];
  const float* be1a = (const float*)d_in[30];
  const float* g2a = (const float*)d_in[31];
  const float* be2a = (const float*)d_in[32];

  // both encoders together, 3 layers
  for (int l = 0; l < 3; ++l) {
    // QKV x2 encoders (z=6)
    for (int j = 0; j < 3; ++j) {
      ga.A[j] = htb;     ga.Bm[j] = Wp[2 + l * 4 + j];
      ga.A[3 + j] = hab; ga.Bm[3 + j] = Wp[20 + l * 4 + j];
    }
    short* outs[6] = {qall, kall, vall, qall + 1048576, kall + 1048576, vall + 1048576};
    for (int j = 0; j < 6; ++j) ga.Cb[j] = outs[j];
    ga.Ndim = 256; ga.Kdim = 256;
    mgemm_kernel<1, false, false><<<dim3(32, 4, 6), 256, 0, stream>>>(ga);
    // attention, 128 head-slots (64 enc-t + 64 enc-a)
    mattn_kernel<0><<<dim3(128, 4, 1), 512, 0, stream>>>(qall, kall, vall, t1b,
                                                         asgn, fullm, padm);
    // wo x2
    ga.A[0] = t1b;           ga.Bm[0] = Wp[2 + l * 4 + 3];  ga.Cf[0] = t2;
    ga.A[1] = t1b + 1048576; ga.Bm[1] = Wp[20 + l * 4 + 3]; ga.Cf[1] = t2 + 1048576;
    ga.Ndim = 256; ga.Kdim = 256;
    mgemm_kernel<0, false, false><<<dim3(32, 4, 2), 256, 0, stream>>>(ga);
    ln_add2_kernel<<<2048, 256, 0, stream>>>(ht, t2, g1t + l * 256, be1t + l * 256, htb,
                                             ha, t2 + 1048576, g1a + l * 256, be1a + l * 256, hab);
    // FFN1 x2 (relu+bias, bf16 out)
    ga.A[0] = htb; ga.Bm[0] = Wp[14 + l]; ga.bias[0] = b1t + l * 1024; ga.Cb[0] = t1b;
    ga.A[1] = hab; ga.Bm[1] = Wp[32 + l]; ga.bias[1] = b1a + l * 1024; ga.Cb[1] = t1b + 4194304;
    ga.Ndim = 1024; ga.Kdim = 256;
    mgemm_kernel<1, true, true><<<dim3(32, 16, 2), 256, 0, stream>>>(ga);
    // FFN2 x2 (bias, f32 out)
    ga.A[0] = t1b;           ga.Bm[0] = Wp[17 + l]; ga.bias[0] = b2t + l * 256; ga.Cf[0] = t2;
    ga.A[1] = t1b + 4194304; ga.Bm[1] = Wp[35 + l]; ga.bias[1] = b2a + l * 256; ga.Cf[1] = t2 + 1048576;
    ga.Ndim = 256; ga.Kdim = 1024;
    mgemm_kernel<0, true, false><<<dim3(32, 4, 2), 256, 0, stream>>>(ga);
    ln_add2_kernel<<<2048, 256, 0, stream>>>(ht, t2, g2t + l * 256, be2t + l * 256, htb,
                                             ha, t2 + 1048576, g2a + l * 256, be2a + l * 256, hab);
  }

  // decoder cross-attention block (ht := h)
  ga.A[0] = htb; ga.Bm[0] = Wp[38]; ga.Cb[0] = qall;
  ga.A[1] = hab; ga.Bm[1] = Wp[39]; ga.Cb[1] = kall;
  ga.A[2] = hab; ga.Bm[2] = Wp[40]; ga.Cb[2] = vall;
  ga.Ndim = 256; ga.Kdim = 256;
  mgemm_kernel<1, false, false><<<dim3(32, 4, 3), 256, 0, stream>>>(ga);
  mattn_kernel<1><<<dim3(64, 4, 1), 512, 0, stream>>>(qall, kall, vall, t1b,
                                                      asgn, fullm, padm);
  ga.A[0] = t1b; ga.Bm[0] = Wp[41]; ga.Cf[0] = t2;
  ga.Ndim = 256; ga.Kdim = 256;
  mgemm_kernel<0, false, false><<<dim3(32, 4, 1), 256, 0, stream>>>(ga);
  ln_add1_kernel<<<1024, 256, 0, stream>>>(ht, t2, de_g1, de_be1, htb);
  ga.A[0] = htb; ga.Bm[0] = Wp[42]; ga.bias[0] = de_b1; ga.Cb[0] = t1b;
  ga.Ndim = 512; ga.Kdim = 256;
  mgemm_kernel<1, true, true><<<dim3(32, 8, 1), 256, 0, stream>>>(ga);
  ga.A[0] = t1b; ga.Bm[0] = Wp[43]; ga.bias[0] = de_b2; ga.Cf[0] = t2;
  ga.Ndim = 256; ga.Kdim = 512;
  mgemm_kernel<0, true, false><<<dim3(32, 4, 1), 256, 0, stream>>>(ga);
  ln_add1_kernel<<<1024, 256, 0, stream>>>(ht, t2, de_g2, de_be2, htb);

  // final scores + softmax + transpose
  ga.A[0] = htb; ga.Bm[0] = Wp[44]; ga.Cb[0] = qall;
  ga.A[1] = hab; ga.Bm[1] = Wp[45]; ga.Cb[1] = kall;
  ga.Ndim = 256; ga.Kdim = 256;
  mgemm_kernel<1, false, false><<<dim3(32, 4, 2), 256, 0, stream>>>(ga);
  for (int b = 0; b < 8; ++b) {
    ga.A[b] = qall + (size_t)b * 131072;
    ga.Bm[b] = kall + (size_t)b * 131072;
    ga.Cf[b] = scores + (size_t)b * 262144;
  }
  ga.Ndim = 512; ga.Kdim = 256;
  mgemm_kernel<0, false, false><<<dim3(4, 8, 8), 256, 0, stream>>>(ga);
  final_kernel<<<4096, 64, 0, stream>>>(scores, asgn, fullm, padm, (float*)d_out);
}